// Round 1
// baseline (6318.406 us; speedup 1.0000x reference)
//
#include <hip/hip_runtime.h>

#define NN 50000
#define NE 800000
#define DD 128
#define ED 32
#define NL 4
#define BN_EPS 1e-5f

#define FMA4(A, H, WV)              \
    A.x = fmaf(H, WV.x, A.x);       \
    A.y = fmaf(H, WV.y, A.y);       \
    A.z = fmaf(H, WV.z, A.z);       \
    A.w = fmaf(H, WV.w, A.w)

// ---------------- edge kernel ----------------
// block = 256 threads, 256 edges per block.
// thread: channels c4..c4+3 (c4 = (t&31)*4), edge slot = t>>5 (8 edges in flight).
// W_edge held fully in registers (32 x float4 = 128 VGPRs) -> inner loop is
// 1 LDS broadcast + 4 FMA per k, no LDS bandwidth bottleneck.
__global__ __launch_bounds__(256) void edge_kernel(
    const float* __restrict__ x, const float* __restrict__ ea,
    const int* __restrict__ esrc, const int* __restrict__ edst,
    const float* __restrict__ We, const float* __restrict__ be,
    float* __restrict__ agg)
{
    __shared__ float eal[256 * ED];   // 32 KB staged edge_attr
    const int t = threadIdx.x;
    const int c4 = (t & 31) * 4;
    const int eoff = t >> 5;
    const int e0 = blockIdx.x * 256;

    // stage edge_attr rows (contiguous 32 KB, coalesced float4)
    for (int i = t * 4; i < 256 * ED; i += 256 * 4)
        *(float4*)&eal[i] = *(const float4*)&ea[(size_t)e0 * ED + i];

    // W columns into registers
    float4 w[ED];
#pragma unroll
    for (int k = 0; k < ED; ++k)
        w[k] = *(const float4*)&We[k * DD + c4];
    const float4 bv = *(const float4*)&be[c4];
    __syncthreads();

#pragma unroll 1
    for (int el = eoff; el < 256; el += 8) {
        const int e = e0 + el;
        const int src = esrc[e];
        const int dst = edst[e];
        float4 acc = bv;
#pragma unroll
        for (int k = 0; k < ED; ++k) {
            const float evv = eal[el * ED + k];
            FMA4(acc, evv, w[k]);
        }
        const float4 xv = *(const float4*)&x[(size_t)src * DD + c4];
        const float m0 = fmaxf(xv.x + acc.x, 0.f);
        const float m1 = fmaxf(xv.y + acc.y, 0.f);
        const float m2 = fmaxf(xv.z + acc.z, 0.f);
        const float m3 = fmaxf(xv.w + acc.w, 0.f);
        float* ap = &agg[(size_t)dst * DD + c4];
        unsafeAtomicAdd(ap + 0, m0);
        unsafeAtomicAdd(ap + 1, m1);
        unsafeAtomicAdd(ap + 2, m2);
        unsafeAtomicAdd(ap + 3, m3);
    }
}

// ---------------- node MLP kernel ----------------
// block = 256 threads, 32 rows per block.
// thread: c4 = (t&31)*4 channels, row group rg = t>>5, rows rg+8*rr (rr=0..3).
// hbuf holds agg on input, h2 on output (in-place safe: rows partitioned by block).
__global__ __launch_bounds__(256) void mlp_kernel(
    const float* __restrict__ x, float* __restrict__ hbuf,
    const float* __restrict__ W1, const float* __restrict__ b1,
    const float* __restrict__ W2, const float* __restrict__ b2,
    float* __restrict__ bns)   // [2*DD]: sums then sumsq
{
    __shared__ float Wl[DD * DD];   // 64 KB
    __shared__ float hb[32 * DD];   // 16 KB
    const int t = threadIdx.x;
    const int r0 = blockIdx.x * 32;

    // stage h = x + agg (zero-pad OOB rows)
    {
        const int c = t & 127, rp = t >> 7;
        for (int r = rp; r < 32; r += 2) {
            const int row = r0 + r;
            float v = 0.f;
            if (row < NN) {
                const size_t g = (size_t)row * DD + c;
                v = x[g] + hbuf[g];
            }
            hb[r * DD + c] = v;
        }
    }
    for (int i = t; i < DD * DD; i += 256) Wl[i] = W1[i];
    __syncthreads();

    const int c4 = (t & 31) * 4, rg = t >> 5;
    float4 acc[4];
    {
        const float4 bv = *(const float4*)&b1[c4];
        acc[0] = bv; acc[1] = bv; acc[2] = bv; acc[3] = bv;
    }
#pragma unroll 4
    for (int k = 0; k < DD; ++k) {
        const float4 wv = *(const float4*)&Wl[k * DD + c4];
        const float h0 = hb[(rg + 0)  * DD + k];
        const float h1 = hb[(rg + 8)  * DD + k];
        const float h2 = hb[(rg + 16) * DD + k];
        const float h3 = hb[(rg + 24) * DD + k];
        FMA4(acc[0], h0, wv);
        FMA4(acc[1], h1, wv);
        FMA4(acc[2], h2, wv);
        FMA4(acc[3], h3, wv);
    }
    __syncthreads();   // all hb reads done

    // write h1 = relu(acc) back into hb; reload Wl with W2
#pragma unroll
    for (int rr = 0; rr < 4; ++rr) {
        float4 v = acc[rr];
        v.x = fmaxf(v.x, 0.f); v.y = fmaxf(v.y, 0.f);
        v.z = fmaxf(v.z, 0.f); v.w = fmaxf(v.w, 0.f);
        *(float4*)&hb[(rg + 8 * rr) * DD + c4] = v;
    }
    for (int i = t; i < DD * DD; i += 256) Wl[i] = W2[i];
    __syncthreads();

    {
        const float4 bv = *(const float4*)&b2[c4];
        acc[0] = bv; acc[1] = bv; acc[2] = bv; acc[3] = bv;
    }
#pragma unroll 4
    for (int k = 0; k < DD; ++k) {
        const float4 wv = *(const float4*)&Wl[k * DD + c4];
        const float h0 = hb[(rg + 0)  * DD + k];
        const float h1 = hb[(rg + 8)  * DD + k];
        const float h2 = hb[(rg + 16) * DD + k];
        const float h3 = hb[(rg + 24) * DD + k];
        FMA4(acc[0], h0, wv);
        FMA4(acc[1], h1, wv);
        FMA4(acc[2], h2, wv);
        FMA4(acc[3], h3, wv);
    }

    // write h2 to global + BN partial sums
    float ps[4] = {0.f, 0.f, 0.f, 0.f};
    float pq[4] = {0.f, 0.f, 0.f, 0.f};
#pragma unroll
    for (int rr = 0; rr < 4; ++rr) {
        const int row = r0 + rg + 8 * rr;
        if (row < NN) {
            *(float4*)&hbuf[(size_t)row * DD + c4] = acc[rr];
            ps[0] += acc[rr].x; pq[0] += acc[rr].x * acc[rr].x;
            ps[1] += acc[rr].y; pq[1] += acc[rr].y * acc[rr].y;
            ps[2] += acc[rr].z; pq[2] += acc[rr].z * acc[rr].z;
            ps[3] += acc[rr].w; pq[3] += acc[rr].w * acc[rr].w;
        }
    }
    __syncthreads();   // hb reads of GEMM2 done, reuse as reduction scratch
#pragma unroll
    for (int j = 0; j < 4; ++j) {
        hb[rg * DD + c4 + j]       = ps[j];
        hb[(8 + rg) * DD + c4 + j] = pq[j];
    }
    __syncthreads();
    if (rg == 0) {
#pragma unroll
        for (int j = 0; j < 4; ++j) {
            float s = 0.f, q = 0.f;
#pragma unroll
            for (int g = 0; g < 8; ++g) {
                s += hb[g * DD + c4 + j];
                q += hb[(8 + g) * DD + c4 + j];
            }
            unsafeAtomicAdd(&bns[c4 + j], s);
            unsafeAtomicAdd(&bns[DD + c4 + j], q);
        }
    }
}

// ---------------- BN apply + ReLU ----------------
__global__ __launch_bounds__(256) void bn_apply(
    const float* __restrict__ h2, const float* __restrict__ bns,
    const float* __restrict__ gamma, const float* __restrict__ beta,
    float* __restrict__ xout)
{
    const size_t i = ((size_t)blockIdx.x * 256 + threadIdx.x) * 4;
    if (i >= (size_t)NN * DD) return;
    const int c4 = (int)(i & 127);
    const float4 hv = *(const float4*)&h2[i];
    const float4 sv = *(const float4*)&bns[c4];
    const float4 qv = *(const float4*)&bns[DD + c4];
    const float4 gv = *(const float4*)&gamma[c4];
    const float4 bv = *(const float4*)&beta[c4];
    const float inv_n = 1.f / (float)NN;
    float4 ov;
    {
        const float m = sv.x * inv_n;
        const float var = qv.x * inv_n - m * m;
        ov.x = fmaxf((hv.x - m) * __frsqrt_rn(var + BN_EPS) * gv.x + bv.x, 0.f);
    }
    {
        const float m = sv.y * inv_n;
        const float var = qv.y * inv_n - m * m;
        ov.y = fmaxf((hv.y - m) * __frsqrt_rn(var + BN_EPS) * gv.y + bv.y, 0.f);
    }
    {
        const float m = sv.z * inv_n;
        const float var = qv.z * inv_n - m * m;
        ov.z = fmaxf((hv.z - m) * __frsqrt_rn(var + BN_EPS) * gv.z + bv.z, 0.f);
    }
    {
        const float m = sv.w * inv_n;
        const float var = qv.w * inv_n - m * m;
        ov.w = fmaxf((hv.w - m) * __frsqrt_rn(var + BN_EPS) * gv.w + bv.w, 0.f);
    }
    *(float4*)&xout[i] = ov;
}

extern "C" void kernel_launch(void* const* d_in, const int* in_sizes, int n_in,
                              void* d_out, int out_size, void* d_ws, size_t ws_size,
                              hipStream_t stream) {
    const float* x0    = (const float*)d_in[0];
    const float* ea    = (const float*)d_in[1];
    const int*   eidx  = (const int*)d_in[2];   // harness delivers integer inputs as int32
    const float* We    = (const float*)d_in[3];
    const float* be    = (const float*)d_in[4];
    const float* W1    = (const float*)d_in[5];
    const float* b1    = (const float*)d_in[6];
    const float* W2    = (const float*)d_in[7];
    const float* b2    = (const float*)d_in[8];
    const float* gamma = (const float*)d_in[9];
    const float* beta  = (const float*)d_in[10];
    float* out = (float*)d_out;
    float* ws  = (float*)d_ws;

    float* agg = ws;                         // NN*DD (doubles as h2 buffer)
    float* xb  = ws + (size_t)NN * DD;       // NN*DD (x ping buffer)
    float* bns = ws + (size_t)2 * NN * DD;   // 2*DD

    const int* esrc = eidx;
    const int* edst = eidx + NE;

    const float* xcur = x0;
    for (int l = 0; l < NL; ++l) {
        hipMemsetAsync(agg, 0, (size_t)NN * DD * sizeof(float), stream);
        hipMemsetAsync(bns, 0, 2 * DD * sizeof(float), stream);
        edge_kernel<<<NE / 256, 256, 0, stream>>>(
            xcur, ea, esrc, edst, We + (size_t)l * ED * DD, be + (size_t)l * DD, agg);
        mlp_kernel<<<(NN + 31) / 32, 256, 0, stream>>>(
            xcur, agg, W1 + (size_t)l * DD * DD, b1 + (size_t)l * DD,
            W2 + (size_t)l * DD * DD, b2 + (size_t)l * DD, bns);
        float* xn = (l == NL - 1) ? out : xb;
        bn_apply<<<(NN * DD / 4 + 255) / 256, 256, 0, stream>>>(
            agg, bns, gamma + (size_t)l * DD, beta + (size_t)l * DD, xn);
        xcur = xn;
    }
}

// Round 2
// 2177.113 us; speedup vs baseline: 2.9022x; 2.9022x over previous
//
#include <hip/hip_runtime.h>

#define NN 50000
#define NE 800000
#define DD 128
#define ED 32
#define NL 4
#define BN_EPS 1e-5f
#define SCAN_B 1024
#define NB ((NN + SCAN_B - 1) / SCAN_B)   // 49

#define FMA4(A, H, WV)              \
    A.x = fmaf(H, WV.x, A.x);       \
    A.y = fmaf(H, WV.y, A.y);       \
    A.z = fmaf(H, WV.z, A.z);       \
    A.w = fmaf(H, WV.w, A.w)

// ---------------- CSR build ----------------
__global__ __launch_bounds__(256) void hist_kernel(
    const int* __restrict__ edst, int* __restrict__ deg)
{
    const int e = blockIdx.x * 256 + threadIdx.x;
    if (e < NE) atomicAdd(&deg[edst[e]], 1);
}

__global__ __launch_bounds__(256) void scan1_kernel(
    const int* __restrict__ deg, int* __restrict__ rowptr, int* __restrict__ bsum)
{
    __shared__ int sh[256];
    const int t = threadIdx.x, b = blockIdx.x;
    const int base = b * SCAN_B + t * 4;
    int v[4];
#pragma unroll
    for (int j = 0; j < 4; ++j) {
        const int idx = base + j;
        v[j] = (idx < NN) ? deg[idx] : 0;
    }
    sh[t] = v[0] + v[1] + v[2] + v[3];
    __syncthreads();
    for (int off = 1; off < 256; off <<= 1) {
        const int val = (t >= off) ? sh[t - off] : 0;
        __syncthreads();
        sh[t] += val;
        __syncthreads();
    }
    int p = (t == 0) ? 0 : sh[t - 1];
#pragma unroll
    for (int j = 0; j < 4; ++j) {
        const int idx = base + j;
        if (idx < NN) rowptr[idx] = p;
        p += v[j];
    }
    if (t == 255) bsum[b] = sh[255];
}

__global__ void scan2_kernel(int* __restrict__ bsum)
{
    if (threadIdx.x == 0) {
        int acc = 0;
        for (int i = 0; i < NB; ++i) { const int v = bsum[i]; bsum[i] = acc; acc += v; }
    }
}

__global__ __launch_bounds__(256) void scan3_kernel(
    int* __restrict__ rowptr, int* __restrict__ cursor, const int* __restrict__ bsum)
{
    const int idx = blockIdx.x * 256 + threadIdx.x;
    if (idx < NN) {
        const int v = rowptr[idx] + bsum[idx / SCAN_B];
        rowptr[idx] = v;
        cursor[idx] = v;
    }
    if (idx == 0) rowptr[NN] = NE;
}

__global__ __launch_bounds__(256) void scatter_kernel(
    const int* __restrict__ esrc, const int* __restrict__ edst,
    int* __restrict__ cursor, int* __restrict__ src_perm, int* __restrict__ eid_perm)
{
    const int e = blockIdx.x * 256 + threadIdx.x;
    if (e < NE) {
        const int d = edst[e];
        const int pos = atomicAdd(&cursor[d], 1);
        src_perm[pos] = esrc[e];
        eid_perm[pos] = e;
    }
}

// ---------------- edge gather kernel (no atomics) ----------------
// block = 256 threads = 8 half-waves; each 32-lane half-wave owns one dst node.
// lane owns 4 channels (c4); W_edge in registers; ea row broadcast via shfl.
__global__ __launch_bounds__(256) void edge_gather_kernel(
    const float* __restrict__ x, const float* __restrict__ ea,
    const int* __restrict__ rowptr, const int* __restrict__ src_perm,
    const int* __restrict__ eid_perm,
    const float* __restrict__ We, const float* __restrict__ be,
    float* __restrict__ agg)
{
    const int t = threadIdx.x;
    const int lane = t & 31;
    const int c4 = lane * 4;
    const int d = blockIdx.x * 8 + (t >> 5);

    float4 w[ED];
#pragma unroll
    for (int k = 0; k < ED; ++k)
        w[k] = *(const float4*)&We[k * DD + c4];
    const float4 bv = *(const float4*)&be[c4];

    const int beg = rowptr[d];
    const int end = rowptr[d + 1];
    float4 acc = {0.f, 0.f, 0.f, 0.f};

    int i = beg;
    int src_n = 0;
    float eav_n = 0.f;
    if (i < end) {
        src_n = src_perm[i];
        const int e = eid_perm[i];
        eav_n = ea[(size_t)e * ED + lane];
    }
    for (; i < end; ++i) {
        const int src = src_n;
        const float eav = eav_n;
        if (i + 1 < end) {
            src_n = src_perm[i + 1];
            const int e = eid_perm[i + 1];
            eav_n = ea[(size_t)e * ED + lane];
        }
        const float4 xv = *(const float4*)&x[(size_t)src * DD + c4];
        float4 m = bv;
#pragma unroll
        for (int k = 0; k < ED; ++k) {
            const float evv = __shfl(eav, k, 32);
            FMA4(m, evv, w[k]);
        }
        acc.x += fmaxf(xv.x + m.x, 0.f);
        acc.y += fmaxf(xv.y + m.y, 0.f);
        acc.z += fmaxf(xv.z + m.z, 0.f);
        acc.w += fmaxf(xv.w + m.w, 0.f);
    }
    *(float4*)&agg[(size_t)d * DD + c4] = acc;
}

// ---------------- node MLP kernel ----------------
__global__ __launch_bounds__(256) void mlp_kernel(
    const float* __restrict__ x, float* __restrict__ hbuf,
    const float* __restrict__ W1, const float* __restrict__ b1,
    const float* __restrict__ W2, const float* __restrict__ b2,
    float* __restrict__ bns)   // [2*DD]: sums then sumsq
{
    __shared__ float Wl[DD * DD];   // 64 KB
    __shared__ float hb[32 * DD];   // 16 KB
    const int t = threadIdx.x;
    const int r0 = blockIdx.x * 32;

    {
        const int c = t & 127, rp = t >> 7;
        for (int r = rp; r < 32; r += 2) {
            const int row = r0 + r;
            float v = 0.f;
            if (row < NN) {
                const size_t g = (size_t)row * DD + c;
                v = x[g] + hbuf[g];
            }
            hb[r * DD + c] = v;
        }
    }
    for (int i = t; i < DD * DD; i += 256) Wl[i] = W1[i];
    __syncthreads();

    const int c4 = (t & 31) * 4, rg = t >> 5;
    float4 acc[4];
    {
        const float4 bv = *(const float4*)&b1[c4];
        acc[0] = bv; acc[1] = bv; acc[2] = bv; acc[3] = bv;
    }
#pragma unroll 4
    for (int k = 0; k < DD; ++k) {
        const float4 wv = *(const float4*)&Wl[k * DD + c4];
        const float h0 = hb[(rg + 0)  * DD + k];
        const float h1 = hb[(rg + 8)  * DD + k];
        const float h2 = hb[(rg + 16) * DD + k];
        const float h3 = hb[(rg + 24) * DD + k];
        FMA4(acc[0], h0, wv);
        FMA4(acc[1], h1, wv);
        FMA4(acc[2], h2, wv);
        FMA4(acc[3], h3, wv);
    }
    __syncthreads();

#pragma unroll
    for (int rr = 0; rr < 4; ++rr) {
        float4 v = acc[rr];
        v.x = fmaxf(v.x, 0.f); v.y = fmaxf(v.y, 0.f);
        v.z = fmaxf(v.z, 0.f); v.w = fmaxf(v.w, 0.f);
        *(float4*)&hb[(rg + 8 * rr) * DD + c4] = v;
    }
    for (int i = t; i < DD * DD; i += 256) Wl[i] = W2[i];
    __syncthreads();

    {
        const float4 bv = *(const float4*)&b2[c4];
        acc[0] = bv; acc[1] = bv; acc[2] = bv; acc[3] = bv;
    }
#pragma unroll 4
    for (int k = 0; k < DD; ++k) {
        const float4 wv = *(const float4*)&Wl[k * DD + c4];
        const float h0 = hb[(rg + 0)  * DD + k];
        const float h1 = hb[(rg + 8)  * DD + k];
        const float h2 = hb[(rg + 16) * DD + k];
        const float h3 = hb[(rg + 24) * DD + k];
        FMA4(acc[0], h0, wv);
        FMA4(acc[1], h1, wv);
        FMA4(acc[2], h2, wv);
        FMA4(acc[3], h3, wv);
    }

    float ps[4] = {0.f, 0.f, 0.f, 0.f};
    float pq[4] = {0.f, 0.f, 0.f, 0.f};
#pragma unroll
    for (int rr = 0; rr < 4; ++rr) {
        const int row = r0 + rg + 8 * rr;
        if (row < NN) {
            *(float4*)&hbuf[(size_t)row * DD + c4] = acc[rr];
            ps[0] += acc[rr].x; pq[0] += acc[rr].x * acc[rr].x;
            ps[1] += acc[rr].y; pq[1] += acc[rr].y * acc[rr].y;
            ps[2] += acc[rr].z; pq[2] += acc[rr].z * acc[rr].z;
            ps[3] += acc[rr].w; pq[3] += acc[rr].w * acc[rr].w;
        }
    }
    __syncthreads();
#pragma unroll
    for (int j = 0; j < 4; ++j) {
        hb[rg * DD + c4 + j]       = ps[j];
        hb[(8 + rg) * DD + c4 + j] = pq[j];
    }
    __syncthreads();
    if (rg == 0) {
#pragma unroll
        for (int j = 0; j < 4; ++j) {
            float s = 0.f, q = 0.f;
#pragma unroll
            for (int g = 0; g < 8; ++g) {
                s += hb[g * DD + c4 + j];
                q += hb[(8 + g) * DD + c4 + j];
            }
            unsafeAtomicAdd(&bns[c4 + j], s);
            unsafeAtomicAdd(&bns[DD + c4 + j], q);
        }
    }
}

// ---------------- BN apply + ReLU ----------------
__global__ __launch_bounds__(256) void bn_apply(
    const float* __restrict__ h2, const float* __restrict__ bns,
    const float* __restrict__ gamma, const float* __restrict__ beta,
    float* __restrict__ xout)
{
    const size_t i = ((size_t)blockIdx.x * 256 + threadIdx.x) * 4;
    if (i >= (size_t)NN * DD) return;
    const int c4 = (int)(i & 127);
    const float4 hv = *(const float4*)&h2[i];
    const float4 sv = *(const float4*)&bns[c4];
    const float4 qv = *(const float4*)&bns[DD + c4];
    const float4 gv = *(const float4*)&gamma[c4];
    const float4 bv = *(const float4*)&beta[c4];
    const float inv_n = 1.f / (float)NN;
    float4 ov;
    {
        const float m = sv.x * inv_n;
        const float var = qv.x * inv_n - m * m;
        ov.x = fmaxf((hv.x - m) * __frsqrt_rn(var + BN_EPS) * gv.x + bv.x, 0.f);
    }
    {
        const float m = sv.y * inv_n;
        const float var = qv.y * inv_n - m * m;
        ov.y = fmaxf((hv.y - m) * __frsqrt_rn(var + BN_EPS) * gv.y + bv.y, 0.f);
    }
    {
        const float m = sv.z * inv_n;
        const float var = qv.z * inv_n - m * m;
        ov.z = fmaxf((hv.z - m) * __frsqrt_rn(var + BN_EPS) * gv.z + bv.z, 0.f);
    }
    {
        const float m = sv.w * inv_n;
        const float var = qv.w * inv_n - m * m;
        ov.w = fmaxf((hv.w - m) * __frsqrt_rn(var + BN_EPS) * gv.w + bv.w, 0.f);
    }
    *(float4*)&xout[i] = ov;
}

extern "C" void kernel_launch(void* const* d_in, const int* in_sizes, int n_in,
                              void* d_out, int out_size, void* d_ws, size_t ws_size,
                              hipStream_t stream) {
    const float* x0    = (const float*)d_in[0];
    const float* ea    = (const float*)d_in[1];
    const int*   eidx  = (const int*)d_in[2];
    const float* We    = (const float*)d_in[3];
    const float* be    = (const float*)d_in[4];
    const float* W1    = (const float*)d_in[5];
    const float* b1    = (const float*)d_in[6];
    const float* W2    = (const float*)d_in[7];
    const float* b2    = (const float*)d_in[8];
    const float* gamma = (const float*)d_in[9];
    const float* beta  = (const float*)d_in[10];
    float* out = (float*)d_out;
    float* ws  = (float*)d_ws;

    float* agg = ws;                           // NN*DD (doubles as h2 buffer)
    float* xb  = agg + (size_t)NN * DD;        // NN*DD
    float* bns = xb + (size_t)NN * DD;         // 2*DD
    int* deg      = (int*)(bns + 2 * DD);      // NN
    int* rowptr   = deg + NN;                  // NN+1
    int* cursor   = rowptr + NN + 1;           // NN
    int* bsum     = cursor + NN;               // 64
    int* src_perm = bsum + 64;                 // NE
    int* eid_perm = src_perm + NE;             // NE

    const int* esrc = eidx;
    const int* edst = eidx + NE;

    // ---- CSR build (once; reused by all 4 layers) ----
    hipMemsetAsync(deg, 0, NN * sizeof(int), stream);
    hist_kernel<<<(NE + 255) / 256, 256, 0, stream>>>(edst, deg);
    scan1_kernel<<<NB, 256, 0, stream>>>(deg, rowptr, bsum);
    scan2_kernel<<<1, 64, 0, stream>>>(bsum);
    scan3_kernel<<<(NN + 255) / 256, 256, 0, stream>>>(rowptr, cursor, bsum);
    scatter_kernel<<<(NE + 255) / 256, 256, 0, stream>>>(esrc, edst, cursor, src_perm, eid_perm);

    const float* xcur = x0;
    for (int l = 0; l < NL; ++l) {
        hipMemsetAsync(bns, 0, 2 * DD * sizeof(float), stream);
        edge_gather_kernel<<<NN / 8, 256, 0, stream>>>(
            xcur, ea, rowptr, src_perm, eid_perm,
            We + (size_t)l * ED * DD, be + (size_t)l * DD, agg);
        mlp_kernel<<<(NN + 31) / 32, 256, 0, stream>>>(
            xcur, agg, W1 + (size_t)l * DD * DD, b1 + (size_t)l * DD,
            W2 + (size_t)l * DD * DD, b2 + (size_t)l * DD, bns);
        float* xn = (l == NL - 1) ? out : xb;
        bn_apply<<<(NN * DD / 4 + 255) / 256, 256, 0, stream>>>(
            agg, bns, gamma + (size_t)l * DD, beta + (size_t)l * DD, xn);
        xcur = xn;
    }
}

// Round 3
// 1372.622 us; speedup vs baseline: 4.6032x; 1.5861x over previous
//
#include <hip/hip_runtime.h>

#define NN 50000
#define NE 800000
#define DD 128
#define ED 32
#define NL 4
#define BN_EPS 1e-5f
#define SCAN_B 1024
#define NB ((NN + SCAN_B - 1) / SCAN_B)   // 49

typedef __attribute__((ext_vector_type(8))) short bf16x8;
typedef __attribute__((ext_vector_type(4))) float f32x4;

__device__ __forceinline__ unsigned short f2bf(float f) {
    unsigned u = __float_as_uint(f);
    u += 0x7fffu + ((u >> 16) & 1u);
    return (unsigned short)(u >> 16);
}

#define FMA4(A, H, WV)              \
    A.x = fmaf(H, WV.x, A.x);       \
    A.y = fmaf(H, WV.y, A.y);       \
    A.z = fmaf(H, WV.z, A.z);       \
    A.w = fmaf(H, WV.w, A.w)

// ---------------- CSR build ----------------
__global__ __launch_bounds__(256) void hist_kernel(
    const int* __restrict__ edst, int* __restrict__ deg)
{
    const int e = blockIdx.x * 256 + threadIdx.x;
    if (e < NE) atomicAdd(&deg[edst[e]], 1);
}

__global__ __launch_bounds__(256) void scan1_kernel(
    const int* __restrict__ deg, int* __restrict__ rowptr, int* __restrict__ bsum)
{
    __shared__ int sh[256];
    const int t = threadIdx.x, b = blockIdx.x;
    const int base = b * SCAN_B + t * 4;
    int v[4];
#pragma unroll
    for (int j = 0; j < 4; ++j) {
        const int idx = base + j;
        v[j] = (idx < NN) ? deg[idx] : 0;
    }
    sh[t] = v[0] + v[1] + v[2] + v[3];
    __syncthreads();
    for (int off = 1; off < 256; off <<= 1) {
        const int val = (t >= off) ? sh[t - off] : 0;
        __syncthreads();
        sh[t] += val;
        __syncthreads();
    }
    int p = (t == 0) ? 0 : sh[t - 1];
#pragma unroll
    for (int j = 0; j < 4; ++j) {
        const int idx = base + j;
        if (idx < NN) rowptr[idx] = p;
        p += v[j];
    }
    if (t == 255) bsum[b] = sh[255];
}

__global__ void scan2_kernel(int* __restrict__ bsum)
{
    if (threadIdx.x == 0) {
        int acc = 0;
        for (int i = 0; i < NB; ++i) { const int v = bsum[i]; bsum[i] = acc; acc += v; }
    }
}

__global__ __launch_bounds__(256) void scan3_kernel(
    int* __restrict__ rowptr, int* __restrict__ cursor, const int* __restrict__ bsum)
{
    const int idx = blockIdx.x * 256 + threadIdx.x;
    if (idx < NN) {
        const int v = rowptr[idx] + bsum[idx / SCAN_B];
        rowptr[idx] = v;
        cursor[idx] = v;
    }
    if (idx == 0) rowptr[NN] = NE;
}

// scatter edges into dst-sorted order; also emit dst-sorted bf16 edge_attr
__global__ __launch_bounds__(256) void scatter_kernel(
    const int* __restrict__ esrc, const int* __restrict__ edst,
    const float* __restrict__ ea, int* __restrict__ cursor,
    int* __restrict__ src_perm, int* __restrict__ dst_perm,
    unsigned short* __restrict__ ea_bf)
{
    const int e = blockIdx.x * 256 + threadIdx.x;
    if (e < NE) {
        const int d = edst[e];
        const int pos = atomicAdd(&cursor[d], 1);
        src_perm[pos] = esrc[e];
        dst_perm[pos] = d;
        const float* er = &ea[(size_t)e * ED];
        unsigned short* ob = &ea_bf[(size_t)pos * ED];
#pragma unroll
        for (int g = 0; g < 8; ++g) {
            const float4 v = *(const float4*)&er[g * 4];
            uint2 p;
            p.x = (unsigned)f2bf(v.x) | ((unsigned)f2bf(v.y) << 16);
            p.y = (unsigned)f2bf(v.z) | ((unsigned)f2bf(v.w) << 16);
            *(uint2*)&ob[g * 4] = p;
        }
    }
}

// W_edge [NL][ED][DD] f32 -> Wt bf16 [NL][DD][ED] (transposed, contiguous in K)
__global__ __launch_bounds__(256) void wconv_kernel(
    const float* __restrict__ We, unsigned short* __restrict__ wtb)
{
    const int tid = blockIdx.x * 256 + threadIdx.x;
    if (tid < NL * DD * ED) {
        const int l = tid / (DD * ED);
        const int r = tid % (DD * ED);
        const int c = r / ED, k = r % ED;
        wtb[tid] = f2bf(We[(size_t)l * ED * DD + k * DD + c]);
    }
}

// ---------------- MFMA edge kernel ----------------
// block = 256 threads = 4 waves, 256 dst-sorted edges per block.
// Phase B: 128x mfma_f32_16x16x32_bf16 -> msg[256][128] bf16 in swizzled LDS.
// Phase C: wave w reduces edges [w*64, w*64+64), lane owns 2 channels;
// interior dst segments plain-store, chunk-boundary segments atomicAdd.
__global__ __launch_bounds__(256) void edge_mfma_kernel(
    const float* __restrict__ x,
    const unsigned short* __restrict__ eab,   // [NE][ED] bf16, dst-sorted
    const int* __restrict__ src_perm,
    const int* __restrict__ dst_perm,
    const unsigned short* __restrict__ wtb,   // [DD][ED] bf16 (layer slice)
    const float* __restrict__ be,
    float* __restrict__ agg)
{
    __shared__ unsigned short msgl[256 * 128];   // 64 KB
    const int t = threadIdx.x;
    const int wv = t >> 6, ln = t & 63;
    const int l15 = ln & 15, kb = ln >> 4;
    const int e0 = blockIdx.x * 256;

    // B fragments: channels cg0 = 2wv*16+l15, cg1 = (2wv+1)*16+l15
    const int c0 = (2 * wv + 0) * 16 + l15;
    const int c1 = (2 * wv + 1) * 16 + l15;
    const bf16x8 bfr0 = *(const bf16x8*)&wtb[c0 * ED + kb * 8];
    const bf16x8 bfr1 = *(const bf16x8*)&wtb[c1 * ED + kb * 8];

    for (int eg = 0; eg < 16; ++eg) {
        const int edge = eg * 16 + l15;
        const bf16x8 afr = *(const bf16x8*)&eab[(size_t)(e0 + edge) * ED + kb * 8];
        f32x4 z = {0.f, 0.f, 0.f, 0.f};
        const f32x4 d0 = __builtin_amdgcn_mfma_f32_16x16x32_bf16(afr, bfr0, z, 0, 0, 0);
        const f32x4 d1 = __builtin_amdgcn_mfma_f32_16x16x32_bf16(afr, bfr1, z, 0, 0, 0);
#pragma unroll
        for (int j = 0; j < 4; ++j) {
            const int mrow = eg * 16 + kb * 4 + j;
            const int sw = ((mrow >> 2) & 3) << 3;       // bank swizzle
            const int i0 = (((c0 >> 1) ^ sw) << 1) | (c0 & 1);
            const int i1 = (((c1 >> 1) ^ sw) << 1) | (c1 & 1);
            msgl[mrow * 128 + i0] = f2bf(d0[j]);
            msgl[mrow * 128 + i1] = f2bf(d1[j]);
        }
    }
    __syncthreads();

    // Phase C: segmented reduce over 64 sorted edges per wave
    const int cbase = e0 + wv * 64;
    const int c2 = ln * 2;
    const float2 bv = *(const float2*)&be[c2];
    float2 acc = {0.f, 0.f};
    int seg_start = 0;
    int dnext = dst_perm[cbase];
    for (int g = 0; g < 8; ++g) {
        const int gb = g * 8;
        int srcs[8], dsts[9];
        dsts[0] = dnext;
#pragma unroll
        for (int q = 1; q < 8; ++q) dsts[q] = dst_perm[cbase + gb + q];
        dsts[8] = (gb + 8 < 64) ? dst_perm[cbase + gb + 8] : -1;
        dnext = dsts[8];
#pragma unroll
        for (int q = 0; q < 8; ++q) srcs[q] = src_perm[cbase + gb + q];
        float2 xv[8];
#pragma unroll
        for (int q = 0; q < 8; ++q)
            xv[q] = *(const float2*)&x[(size_t)srcs[q] * DD + c2];
#pragma unroll
        for (int q = 0; q < 8; ++q) {
            const int i = gb + q;
            const int dw = ln ^ (((i >> 2) & 3) << 3);
            const unsigned mm = *(const unsigned*)&msgl[(wv * 64 + i) * 128 + dw * 2];
            const float mlo = __uint_as_float(mm << 16);
            const float mhi = __uint_as_float(mm & 0xffff0000u);
            acc.x += fmaxf(xv[q].x + mlo + bv.x, 0.f);
            acc.y += fmaxf(xv[q].y + mhi + bv.y, 0.f);
            if (i == 63 || dsts[q + 1] != dsts[q]) {
                float* ap = &agg[(size_t)dsts[q] * DD + c2];
                if (seg_start > 0 && i < 63) {
                    *(float2*)ap = acc;             // interior: sole writer
                } else {
                    unsafeAtomicAdd(ap + 0, acc.x); // chunk-boundary segment
                    unsafeAtomicAdd(ap + 1, acc.y);
                }
                acc.x = 0.f; acc.y = 0.f;
                seg_start = i + 1;
            }
        }
    }
}

// ---------------- node MLP kernel ----------------
__global__ __launch_bounds__(256) void mlp_kernel(
    const float* __restrict__ x, float* __restrict__ hbuf,
    const float* __restrict__ W1, const float* __restrict__ b1,
    const float* __restrict__ W2, const float* __restrict__ b2,
    float* __restrict__ bns)   // [2*DD]: sums then sumsq
{
    __shared__ float Wl[DD * DD];   // 64 KB
    __shared__ float hb[32 * DD];   // 16 KB
    const int t = threadIdx.x;
    const int r0 = blockIdx.x * 32;

    {
        const int c = t & 127, rp = t >> 7;
        for (int r = rp; r < 32; r += 2) {
            const int row = r0 + r;
            float v = 0.f;
            if (row < NN) {
                const size_t g = (size_t)row * DD + c;
                v = x[g] + hbuf[g];
            }
            hb[r * DD + c] = v;
        }
    }
    for (int i = t; i < DD * DD; i += 256) Wl[i] = W1[i];
    __syncthreads();

    const int c4 = (t & 31) * 4, rg = t >> 5;
    float4 acc[4];
    {
        const float4 bv = *(const float4*)&b1[c4];
        acc[0] = bv; acc[1] = bv; acc[2] = bv; acc[3] = bv;
    }
#pragma unroll 4
    for (int k = 0; k < DD; ++k) {
        const float4 wv = *(const float4*)&Wl[k * DD + c4];
        const float h0 = hb[(rg + 0)  * DD + k];
        const float h1 = hb[(rg + 8)  * DD + k];
        const float h2 = hb[(rg + 16) * DD + k];
        const float h3 = hb[(rg + 24) * DD + k];
        FMA4(acc[0], h0, wv);
        FMA4(acc[1], h1, wv);
        FMA4(acc[2], h2, wv);
        FMA4(acc[3], h3, wv);
    }
    __syncthreads();

#pragma unroll
    for (int rr = 0; rr < 4; ++rr) {
        float4 v = acc[rr];
        v.x = fmaxf(v.x, 0.f); v.y = fmaxf(v.y, 0.f);
        v.z = fmaxf(v.z, 0.f); v.w = fmaxf(v.w, 0.f);
        *(float4*)&hb[(rg + 8 * rr) * DD + c4] = v;
    }
    for (int i = t; i < DD * DD; i += 256) Wl[i] = W2[i];
    __syncthreads();

    {
        const float4 bv = *(const float4*)&b2[c4];
        acc[0] = bv; acc[1] = bv; acc[2] = bv; acc[3] = bv;
    }
#pragma unroll 4
    for (int k = 0; k < DD; ++k) {
        const float4 wv = *(const float4*)&Wl[k * DD + c4];
        const float h0 = hb[(rg + 0)  * DD + k];
        const float h1 = hb[(rg + 8)  * DD + k];
        const float h2 = hb[(rg + 16) * DD + k];
        const float h3 = hb[(rg + 24) * DD + k];
        FMA4(acc[0], h0, wv);
        FMA4(acc[1], h1, wv);
        FMA4(acc[2], h2, wv);
        FMA4(acc[3], h3, wv);
    }

    float ps[4] = {0.f, 0.f, 0.f, 0.f};
    float pq[4] = {0.f, 0.f, 0.f, 0.f};
#pragma unroll
    for (int rr = 0; rr < 4; ++rr) {
        const int row = r0 + rg + 8 * rr;
        if (row < NN) {
            *(float4*)&hbuf[(size_t)row * DD + c4] = acc[rr];
            ps[0] += acc[rr].x; pq[0] += acc[rr].x * acc[rr].x;
            ps[1] += acc[rr].y; pq[1] += acc[rr].y * acc[rr].y;
            ps[2] += acc[rr].z; pq[2] += acc[rr].z * acc[rr].z;
            ps[3] += acc[rr].w; pq[3] += acc[rr].w * acc[rr].w;
        }
    }
    __syncthreads();
#pragma unroll
    for (int j = 0; j < 4; ++j) {
        hb[rg * DD + c4 + j]       = ps[j];
        hb[(8 + rg) * DD + c4 + j] = pq[j];
    }
    __syncthreads();
    if (rg == 0) {
#pragma unroll
        for (int j = 0; j < 4; ++j) {
            float s = 0.f, q = 0.f;
#pragma unroll
            for (int g = 0; g < 8; ++g) {
                s += hb[g * DD + c4 + j];
                q += hb[(8 + g) * DD + c4 + j];
            }
            unsafeAtomicAdd(&bns[c4 + j], s);
            unsafeAtomicAdd(&bns[DD + c4 + j], q);
        }
    }
}

// ---------------- BN apply + ReLU ----------------
__global__ __launch_bounds__(256) void bn_apply(
    const float* __restrict__ h2, const float* __restrict__ bns,
    const float* __restrict__ gamma, const float* __restrict__ beta,
    float* __restrict__ xout)
{
    const size_t i = ((size_t)blockIdx.x * 256 + threadIdx.x) * 4;
    if (i >= (size_t)NN * DD) return;
    const int c4 = (int)(i & 127);
    const float4 hv = *(const float4*)&h2[i];
    const float4 sv = *(const float4*)&bns[c4];
    const float4 qv = *(const float4*)&bns[DD + c4];
    const float4 gv = *(const float4*)&gamma[c4];
    const float4 bv = *(const float4*)&beta[c4];
    const float inv_n = 1.f / (float)NN;
    float4 ov;
    {
        const float m = sv.x * inv_n;
        const float var = qv.x * inv_n - m * m;
        ov.x = fmaxf((hv.x - m) * __frsqrt_rn(var + BN_EPS) * gv.x + bv.x, 0.f);
    }
    {
        const float m = sv.y * inv_n;
        const float var = qv.y * inv_n - m * m;
        ov.y = fmaxf((hv.y - m) * __frsqrt_rn(var + BN_EPS) * gv.y + bv.y, 0.f);
    }
    {
        const float m = sv.z * inv_n;
        const float var = qv.z * inv_n - m * m;
        ov.z = fmaxf((hv.z - m) * __frsqrt_rn(var + BN_EPS) * gv.z + bv.z, 0.f);
    }
    {
        const float m = sv.w * inv_n;
        const float var = qv.w * inv_n - m * m;
        ov.w = fmaxf((hv.w - m) * __frsqrt_rn(var + BN_EPS) * gv.w + bv.w, 0.f);
    }
    *(float4*)&xout[i] = ov;
}

extern "C" void kernel_launch(void* const* d_in, const int* in_sizes, int n_in,
                              void* d_out, int out_size, void* d_ws, size_t ws_size,
                              hipStream_t stream) {
    const float* x0    = (const float*)d_in[0];
    const float* ea    = (const float*)d_in[1];
    const int*   eidx  = (const int*)d_in[2];
    const float* We    = (const float*)d_in[3];
    const float* be    = (const float*)d_in[4];
    const float* W1    = (const float*)d_in[5];
    const float* b1    = (const float*)d_in[6];
    const float* W2    = (const float*)d_in[7];
    const float* b2    = (const float*)d_in[8];
    const float* gamma = (const float*)d_in[9];
    const float* beta  = (const float*)d_in[10];
    float* out = (float*)d_out;
    float* ws  = (float*)d_ws;

    float* agg = ws;                              // NN*DD (doubles as h2)
    float* xb  = agg + (size_t)NN * DD;           // NN*DD
    float* bns = xb + (size_t)NN * DD;            // 2*DD
    int* deg      = (int*)(bns + 2 * DD);         // NN
    int* rowptr   = deg + NN;                     // NN+1
    int* cursor   = rowptr + NN + 1;              // NN
    int* bsum     = cursor + NN;                  // 64
    int* src_perm = bsum + 64;                    // NE
    int* dst_perm = src_perm + NE;                // NE
    unsigned short* ea_bf = (unsigned short*)(dst_perm + NE);  // NE*ED bf16
    unsigned short* wt_bf = ea_bf + (size_t)NE * ED;           // NL*DD*ED bf16

    const int* esrc = eidx;
    const int* edst = eidx + NE;

    // ---- CSR build + bf16 pre-conversion (once; reused by all 4 layers) ----
    hipMemsetAsync(deg, 0, NN * sizeof(int), stream);
    hist_kernel<<<(NE + 255) / 256, 256, 0, stream>>>(edst, deg);
    scan1_kernel<<<NB, 256, 0, stream>>>(deg, rowptr, bsum);
    scan2_kernel<<<1, 64, 0, stream>>>(bsum);
    scan3_kernel<<<(NN + 255) / 256, 256, 0, stream>>>(rowptr, cursor, bsum);
    scatter_kernel<<<(NE + 255) / 256, 256, 0, stream>>>(
        esrc, edst, ea, cursor, src_perm, dst_perm, ea_bf);
    wconv_kernel<<<(NL * DD * ED + 255) / 256, 256, 0, stream>>>(We, wt_bf);

    const float* xcur = x0;
    for (int l = 0; l < NL; ++l) {
        hipMemsetAsync(agg, 0, (size_t)NN * DD * sizeof(float), stream);
        hipMemsetAsync(bns, 0, 2 * DD * sizeof(float), stream);
        edge_mfma_kernel<<<NE / 256, 256, 0, stream>>>(
            xcur, ea_bf, src_perm, dst_perm,
            wt_bf + (size_t)l * DD * ED, be + (size_t)l * DD, agg);
        mlp_kernel<<<(NN + 31) / 32, 256, 0, stream>>>(
            xcur, agg, W1 + (size_t)l * DD * DD, b1 + (size_t)l * DD,
            W2 + (size_t)l * DD * DD, b2 + (size_t)l * DD, bns);
        float* xn = (l == NL - 1) ? out : xb;
        bn_apply<<<(NN * DD / 4 + 255) / 256, 256, 0, stream>>>(
            agg, bns, gamma + (size_t)l * DD, beta + (size_t)l * DD, xn);
        xcur = xn;
    }
}

// Round 5
// 736.549 us; speedup vs baseline: 8.5784x; 1.8636x over previous
//
#include <hip/hip_runtime.h>

#define NN 50000
#define NE 800000
#define DD 128
#define ED 32
#define NL 4
#define BN_EPS 1e-5f
#define SCAN_B 1024
#define NB ((NN + SCAN_B - 1) / SCAN_B)   // 49

typedef __attribute__((ext_vector_type(8))) short bf16x8;
typedef __attribute__((ext_vector_type(4))) float f32x4;

__device__ __forceinline__ unsigned short f2bf(float f) {
    unsigned u = __float_as_uint(f);
    u += 0x7fffu + ((u >> 16) & 1u);
    return (unsigned short)(u >> 16);
}
__device__ __forceinline__ float bf2f(unsigned short h) {
    return __uint_as_float((unsigned)h << 16);
}

// ---------------- CSR build ----------------
__global__ __launch_bounds__(256) void hist_kernel(
    const int* __restrict__ edst, int* __restrict__ deg)
{
    const int e = blockIdx.x * 256 + threadIdx.x;
    if (e < NE) atomicAdd(&deg[edst[e]], 1);
}

__global__ __launch_bounds__(256) void scan1_kernel(
    const int* __restrict__ deg, int* __restrict__ rowptr, int* __restrict__ bsum)
{
    __shared__ int sh[256];
    const int t = threadIdx.x, b = blockIdx.x;
    const int base = b * SCAN_B + t * 4;
    int v[4];
#pragma unroll
    for (int j = 0; j < 4; ++j) {
        const int idx = base + j;
        v[j] = (idx < NN) ? deg[idx] : 0;
    }
    sh[t] = v[0] + v[1] + v[2] + v[3];
    __syncthreads();
    for (int off = 1; off < 256; off <<= 1) {
        const int val = (t >= off) ? sh[t - off] : 0;
        __syncthreads();
        sh[t] += val;
        __syncthreads();
    }
    int p = (t == 0) ? 0 : sh[t - 1];
#pragma unroll
    for (int j = 0; j < 4; ++j) {
        const int idx = base + j;
        if (idx < NN) rowptr[idx] = p;
        p += v[j];
    }
    if (t == 255) bsum[b] = sh[255];
}

__global__ void scan2_kernel(int* __restrict__ bsum)
{
    if (threadIdx.x == 0) {
        int acc = 0;
        for (int i = 0; i < NB; ++i) { const int v = bsum[i]; bsum[i] = acc; acc += v; }
    }
}

__global__ __launch_bounds__(256) void scan3_kernel(
    int* __restrict__ rowptr, int* __restrict__ cursor, const int* __restrict__ bsum)
{
    const int idx = blockIdx.x * 256 + threadIdx.x;
    if (idx < NN) {
        const int v = rowptr[idx] + bsum[idx / SCAN_B];
        rowptr[idx] = v;
        cursor[idx] = v;
    }
    if (idx == 0) rowptr[NN] = NE;
}

// scatter edges into dst-sorted order; also emit dst-sorted bf16 edge_attr
__global__ __launch_bounds__(256) void scatter_kernel(
    const int* __restrict__ esrc, const int* __restrict__ edst,
    const float* __restrict__ ea, int* __restrict__ cursor,
    int* __restrict__ src_perm, int* __restrict__ dst_perm,
    unsigned short* __restrict__ ea_bf)
{
    const int e = blockIdx.x * 256 + threadIdx.x;
    if (e < NE) {
        const int d = edst[e];
        const int pos = atomicAdd(&cursor[d], 1);
        src_perm[pos] = esrc[e];
        dst_perm[pos] = d;
        const float* er = &ea[(size_t)e * ED];
        unsigned short* ob = &ea_bf[(size_t)pos * ED];
#pragma unroll
        for (int g = 0; g < 8; ++g) {
            const float4 v = *(const float4*)&er[g * 4];
            uint2 p;
            p.x = (unsigned)f2bf(v.x) | ((unsigned)f2bf(v.y) << 16);
            p.y = (unsigned)f2bf(v.z) | ((unsigned)f2bf(v.w) << 16);
            *(uint2*)&ob[g * 4] = p;
        }
    }
}

// W_edge [NL][ED][DD] f32 -> wtb bf16 [NL][DD][ED] (transposed, contiguous in K)
__global__ __launch_bounds__(256) void wconv_kernel(
    const float* __restrict__ We, unsigned short* __restrict__ wtb)
{
    const int tid = blockIdx.x * 256 + threadIdx.x;
    if (tid < NL * DD * ED) {
        const int l = tid / (DD * ED);
        const int r = tid % (DD * ED);
        const int c = r / ED, k = r % ED;
        wtb[tid] = f2bf(We[(size_t)l * ED * DD + k * DD + c]);
    }
}

// W1/W2 [NL][DD][DD] f32 ([k][n]) -> bf16 [NL][DD][DD] ([n][k])
__global__ __launch_bounds__(256) void w12conv_kernel(
    const float* __restrict__ W1, const float* __restrict__ W2,
    unsigned short* __restrict__ w1t, unsigned short* __restrict__ w2t)
{
    const int tid = blockIdx.x * 256 + threadIdx.x;
    if (tid < NL * DD * DD) {
        const int l = tid / (DD * DD);
        const int r = tid % (DD * DD);
        const int n = r / DD, k = r % DD;
        const size_t s = (size_t)l * DD * DD + k * DD + n;
        w1t[tid] = f2bf(W1[s]);
        w2t[tid] = f2bf(W2[s]);
    }
}

// ---------------- MFMA edge kernel ----------------
__global__ __launch_bounds__(256) void edge_mfma_kernel(
    const float* __restrict__ x,
    const unsigned short* __restrict__ eab,   // [NE][ED] bf16, dst-sorted
    const int* __restrict__ src_perm,
    const int* __restrict__ dst_perm,
    const unsigned short* __restrict__ wtb,   // [DD][ED] bf16 (layer slice)
    const float* __restrict__ be,
    float* __restrict__ agg)
{
    __shared__ unsigned short msgl[256 * 128];   // 64 KB
    const int t = threadIdx.x;
    const int wv = t >> 6, ln = t & 63;
    const int l15 = ln & 15, kb = ln >> 4;
    const int e0 = blockIdx.x * 256;

    const int c0 = (2 * wv + 0) * 16 + l15;
    const int c1 = (2 * wv + 1) * 16 + l15;
    const bf16x8 bfr0 = *(const bf16x8*)&wtb[c0 * ED + kb * 8];
    const bf16x8 bfr1 = *(const bf16x8*)&wtb[c1 * ED + kb * 8];

    for (int eg = 0; eg < 16; ++eg) {
        const int edge = eg * 16 + l15;
        const bf16x8 afr = *(const bf16x8*)&eab[(size_t)(e0 + edge) * ED + kb * 8];
        f32x4 z = {0.f, 0.f, 0.f, 0.f};
        const f32x4 d0 = __builtin_amdgcn_mfma_f32_16x16x32_bf16(afr, bfr0, z, 0, 0, 0);
        const f32x4 d1 = __builtin_amdgcn_mfma_f32_16x16x32_bf16(afr, bfr1, z, 0, 0, 0);
#pragma unroll
        for (int j = 0; j < 4; ++j) {
            const int mrow = eg * 16 + kb * 4 + j;
            const int sw = ((mrow >> 2) & 3) << 3;
            const int i0 = (((c0 >> 1) ^ sw) << 1) | (c0 & 1);
            const int i1 = (((c1 >> 1) ^ sw) << 1) | (c1 & 1);
            msgl[mrow * 128 + i0] = f2bf(d0[j]);
            msgl[mrow * 128 + i1] = f2bf(d1[j]);
        }
    }
    __syncthreads();

    const int cbase = e0 + wv * 64;
    const int c2 = ln * 2;
    const float2 bv = *(const float2*)&be[c2];
    float2 acc = {0.f, 0.f};
    int seg_start = 0;
    int dnext = dst_perm[cbase];
    for (int g = 0; g < 8; ++g) {
        const int gb = g * 8;
        int srcs[8], dsts[9];
        dsts[0] = dnext;
#pragma unroll
        for (int q = 1; q < 8; ++q) dsts[q] = dst_perm[cbase + gb + q];
        dsts[8] = (gb + 8 < 64) ? dst_perm[cbase + gb + 8] : -1;
        dnext = dsts[8];
#pragma unroll
        for (int q = 0; q < 8; ++q) srcs[q] = src_perm[cbase + gb + q];
        float2 xv[8];
#pragma unroll
        for (int q = 0; q < 8; ++q)
            xv[q] = *(const float2*)&x[(size_t)srcs[q] * DD + c2];
#pragma unroll
        for (int q = 0; q < 8; ++q) {
            const int i = gb + q;
            const int dw = ln ^ (((i >> 2) & 3) << 3);
            const unsigned mm = *(const unsigned*)&msgl[(wv * 64 + i) * 128 + dw * 2];
            const float mlo = __uint_as_float(mm << 16);
            const float mhi = __uint_as_float(mm & 0xffff0000u);
            acc.x += fmaxf(xv[q].x + mlo + bv.x, 0.f);
            acc.y += fmaxf(xv[q].y + mhi + bv.y, 0.f);
            if (i == 63 || dsts[q + 1] != dsts[q]) {
                float* ap = &agg[(size_t)dsts[q] * DD + c2];
                if (seg_start > 0 && i < 63) {
                    *(float2*)ap = acc;
                } else {
                    unsafeAtomicAdd(ap + 0, acc.x);
                    unsafeAtomicAdd(ap + 1, acc.y);
                }
                acc.x = 0.f; acc.y = 0.f;
                seg_start = i + 1;
            }
        }
    }
}

// ---------------- MFMA node MLP kernel ----------------
// block = 256 = 4 waves; 64 rows/block; wave w owns output cols [w*32, w*32+32).
// A (h, h1) staged in LDS as split bf16 (hi + lo residual), XOR-swizzled
// 8-elem granules (g ^= row&7) for conflict-free ds_read_b128.
__global__ __launch_bounds__(256) void mlp_mfma_kernel(
    const float* __restrict__ x, const float* __restrict__ agg,
    float* __restrict__ h2out,
    const unsigned short* __restrict__ w1t,   // [DD][DD] bf16 [n][k] (layer slice)
    const unsigned short* __restrict__ w2t,
    const float* __restrict__ b1, const float* __restrict__ b2,
    float* __restrict__ bns)
{
    __shared__ unsigned short ah[64 * 128];  // 16 KB h hi
    __shared__ unsigned short al[64 * 128];  // 16 KB h lo
    __shared__ unsigned short bh[64 * 128];  // 16 KB h1 hi
    __shared__ unsigned short bl[64 * 128];  // 16 KB h1 lo
    const int t = threadIdx.x;
    const int wv = t >> 6, ln = t & 63, l15 = ln & 15, kb = ln >> 4;
    const int r0 = blockIdx.x * 64;

    // ---- stage h = x + agg -> split bf16, swizzled ----
    // FIX vs R3: 4 passes x (16 rows, 16 granules) covers all 64x128 elements
    // (R3's 2x(32 rows, 8 granules) left channels 64..127 uninitialized).
#pragma unroll
    for (int p = 0; p < 4; ++p) {
        const int row = p * 16 + (t >> 4);
        const int gc = t & 15;
        const int grow = r0 + row;
        float v[8] = {0.f, 0.f, 0.f, 0.f, 0.f, 0.f, 0.f, 0.f};
        if (grow < NN) {
            const size_t g = (size_t)grow * DD + gc * 8;
            const float4 xa = *(const float4*)&x[g];
            const float4 xc = *(const float4*)&x[g + 4];
            const float4 ga = *(const float4*)&agg[g];
            const float4 gc4 = *(const float4*)&agg[g + 4];
            v[0] = xa.x + ga.x; v[1] = xa.y + ga.y; v[2] = xa.z + ga.z; v[3] = xa.w + ga.w;
            v[4] = xc.x + gc4.x; v[5] = xc.y + gc4.y; v[6] = xc.z + gc4.z; v[7] = xc.w + gc4.w;
        }
        unsigned hiw[4], low[4];
#pragma unroll
        for (int j = 0; j < 4; ++j) {
            const unsigned short h0 = f2bf(v[2 * j]);
            const unsigned short h1 = f2bf(v[2 * j + 1]);
            const unsigned short q0 = f2bf(v[2 * j] - bf2f(h0));
            const unsigned short q1 = f2bf(v[2 * j + 1] - bf2f(h1));
            hiw[j] = (unsigned)h0 | ((unsigned)h1 << 16);
            low[j] = (unsigned)q0 | ((unsigned)q1 << 16);
        }
        const int off = row * 128 + (gc ^ (row & 7)) * 8;
        *(uint4*)&ah[off] = *(uint4*)hiw;
        *(uint4*)&al[off] = *(uint4*)low;
    }

    // B fragments for GEMM1
    bf16x8 w1f[2][4];
#pragma unroll
    for (int nt = 0; nt < 2; ++nt) {
        const int n = wv * 32 + nt * 16 + l15;
#pragma unroll
        for (int ks = 0; ks < 4; ++ks)
            w1f[nt][ks] = *(const bf16x8*)&w1t[n * DD + ks * 32 + kb * 8];
    }
    const int cA = wv * 32 + l15, cB = wv * 32 + 16 + l15;
    const float b1v[2] = {b1[cA], b1[cB]};
    const float b2v[2] = {b2[cA], b2[cB]};
    __syncthreads();

    // ---- GEMM1 ----
    f32x4 acc[4][2];
#pragma unroll
    for (int mt = 0; mt < 4; ++mt)
#pragma unroll
        for (int nt = 0; nt < 2; ++nt)
            acc[mt][nt] = (f32x4){0.f, 0.f, 0.f, 0.f};
#pragma unroll
    for (int ks = 0; ks < 4; ++ks) {
#pragma unroll
        for (int mt = 0; mt < 4; ++mt) {
            const int row = mt * 16 + l15;
            const int off = row * 128 + ((ks * 4 + kb) ^ (row & 7)) * 8;
            const bf16x8 afh = *(const bf16x8*)&ah[off];
            const bf16x8 afl = *(const bf16x8*)&al[off];
#pragma unroll
            for (int nt = 0; nt < 2; ++nt) {
                acc[mt][nt] = __builtin_amdgcn_mfma_f32_16x16x32_bf16(afh, w1f[nt][ks], acc[mt][nt], 0, 0, 0);
                acc[mt][nt] = __builtin_amdgcn_mfma_f32_16x16x32_bf16(afl, w1f[nt][ks], acc[mt][nt], 0, 0, 0);
            }
        }
    }

    // ---- h1 = relu(acc + b1) -> split bf16 LDS ----
#pragma unroll
    for (int mt = 0; mt < 4; ++mt) {
#pragma unroll
        for (int nt = 0; nt < 2; ++nt) {
            const int col = wv * 32 + nt * 16 + l15;
#pragma unroll
            for (int j = 0; j < 4; ++j) {
                const int row = mt * 16 + kb * 4 + j;
                const float v = fmaxf(acc[mt][nt][j] + b1v[nt], 0.f);
                const unsigned short hi = f2bf(v);
                const int off = row * 128 + ((col >> 3) ^ (row & 7)) * 8 + (col & 7);
                bh[off] = hi;
                bl[off] = f2bf(v - bf2f(hi));
            }
        }
    }

    // B fragments for GEMM2
    bf16x8 w2f[2][4];
#pragma unroll
    for (int nt = 0; nt < 2; ++nt) {
        const int n = wv * 32 + nt * 16 + l15;
#pragma unroll
        for (int ks = 0; ks < 4; ++ks)
            w2f[nt][ks] = *(const bf16x8*)&w2t[n * DD + ks * 32 + kb * 8];
    }
    __syncthreads();

    // ---- GEMM2 ----
#pragma unroll
    for (int mt = 0; mt < 4; ++mt)
#pragma unroll
        for (int nt = 0; nt < 2; ++nt)
            acc[mt][nt] = (f32x4){0.f, 0.f, 0.f, 0.f};
#pragma unroll
    for (int ks = 0; ks < 4; ++ks) {
#pragma unroll
        for (int mt = 0; mt < 4; ++mt) {
            const int row = mt * 16 + l15;
            const int off = row * 128 + ((ks * 4 + kb) ^ (row & 7)) * 8;
            const bf16x8 afh = *(const bf16x8*)&bh[off];
            const bf16x8 afl = *(const bf16x8*)&bl[off];
#pragma unroll
            for (int nt = 0; nt < 2; ++nt) {
                acc[mt][nt] = __builtin_amdgcn_mfma_f32_16x16x32_bf16(afh, w2f[nt][ks], acc[mt][nt], 0, 0, 0);
                acc[mt][nt] = __builtin_amdgcn_mfma_f32_16x16x32_bf16(afl, w2f[nt][ks], acc[mt][nt], 0, 0, 0);
            }
        }
    }

    // ---- epilogue: h2 store + BN partial sums ----
    float ps[2] = {0.f, 0.f}, pq[2] = {0.f, 0.f};
#pragma unroll
    for (int mt = 0; mt < 4; ++mt) {
#pragma unroll
        for (int nt = 0; nt < 2; ++nt) {
            const int col = wv * 32 + nt * 16 + l15;
#pragma unroll
            for (int j = 0; j < 4; ++j) {
                const int row = r0 + mt * 16 + kb * 4 + j;
                const float v = acc[mt][nt][j] + b2v[nt];
                if (row < NN) {
                    h2out[(size_t)row * DD + col] = v;
                    ps[nt] += v;
                    pq[nt] += v * v;
                }
            }
        }
    }
#pragma unroll
    for (int nt = 0; nt < 2; ++nt) {
        ps[nt] += __shfl_xor(ps[nt], 16);
        ps[nt] += __shfl_xor(ps[nt], 32);
        pq[nt] += __shfl_xor(pq[nt], 16);
        pq[nt] += __shfl_xor(pq[nt], 32);
    }
    if (kb == 0) {
#pragma unroll
        for (int nt = 0; nt < 2; ++nt) {
            const int col = wv * 32 + nt * 16 + l15;
            unsafeAtomicAdd(&bns[col], ps[nt]);
            unsafeAtomicAdd(&bns[DD + col], pq[nt]);
        }
    }
}

// ---------------- BN apply + ReLU ----------------
__global__ __launch_bounds__(256) void bn_apply(
    const float* __restrict__ h2, const float* __restrict__ bns,
    const float* __restrict__ gamma, const float* __restrict__ beta,
    float* __restrict__ xout)
{
    const size_t i = ((size_t)blockIdx.x * 256 + threadIdx.x) * 4;
    if (i >= (size_t)NN * DD) return;
    const int c4 = (int)(i & 127);
    const float4 hv = *(const float4*)&h2[i];
    const float4 sv = *(const float4*)&bns[c4];
    const float4 qv = *(const float4*)&bns[DD + c4];
    const float4 gv = *(const float4*)&gamma[c4];
    const float4 bv = *(const float4*)&beta[c4];
    const float inv_n = 1.f / (float)NN;
    float4 ov;
    {
        const float m = sv.x * inv_n;
        const float var = qv.x * inv_n - m * m;
        ov.x = fmaxf((hv.x - m) * __frsqrt_rn(var + BN_EPS) * gv.x + bv.x, 0.f);
    }
    {
        const float m = sv.y * inv_n;
        const float var = qv.y * inv_n - m * m;
        ov.y = fmaxf((hv.y - m) * __frsqrt_rn(var + BN_EPS) * gv.y + bv.y, 0.f);
    }
    {
        const float m = sv.z * inv_n;
        const float var = qv.z * inv_n - m * m;
        ov.z = fmaxf((hv.z - m) * __frsqrt_rn(var + BN_EPS) * gv.z + bv.z, 0.f);
    }
    {
        const float m = sv.w * inv_n;
        const float var = qv.w * inv_n - m * m;
        ov.w = fmaxf((hv.w - m) * __frsqrt_rn(var + BN_EPS) * gv.w + bv.w, 0.f);
    }
    *(float4*)&xout[i] = ov;
}

extern "C" void kernel_launch(void* const* d_in, const int* in_sizes, int n_in,
                              void* d_out, int out_size, void* d_ws, size_t ws_size,
                              hipStream_t stream) {
    const float* x0    = (const float*)d_in[0];
    const float* ea    = (const float*)d_in[1];
    const int*   eidx  = (const int*)d_in[2];
    const float* We    = (const float*)d_in[3];
    const float* be    = (const float*)d_in[4];
    const float* W1    = (const float*)d_in[5];
    const float* b1    = (const float*)d_in[6];
    const float* W2    = (const float*)d_in[7];
    const float* b2    = (const float*)d_in[8];
    const float* gamma = (const float*)d_in[9];
    const float* beta  = (const float*)d_in[10];
    float* out = (float*)d_out;
    float* ws  = (float*)d_ws;

    float* agg = ws;                              // NN*DD (doubles as h2)
    float* xb  = agg + (size_t)NN * DD;           // NN*DD
    float* bns = xb + (size_t)NN * DD;            // 256
    int* deg      = (int*)(bns + 256);            // 50000
    int* rowptr   = deg + 50000;                  // 50004 (padded)
    int* cursor   = rowptr + 50004;               // 50000
    int* bsum     = cursor + 50000;               // 64
    int* src_perm = bsum + 64;                    // NE
    int* dst_perm = src_perm + NE;                // NE
    unsigned short* ea_bf = (unsigned short*)(dst_perm + NE);  // NE*ED
    unsigned short* wt_bf = ea_bf + (size_t)NE * ED;           // NL*DD*ED
    unsigned short* w1t   = wt_bf + (size_t)NL * DD * ED;      // NL*DD*DD
    unsigned short* w2t   = w1t + (size_t)NL * DD * DD;        // NL*DD*DD

    const int* esrc = eidx;
    const int* edst = eidx + NE;

    // ---- CSR build + bf16 pre-conversion (once; reused by all 4 layers) ----
    hipMemsetAsync(deg, 0, NN * sizeof(int), stream);
    hist_kernel<<<(NE + 255) / 256, 256, 0, stream>>>(edst, deg);
    scan1_kernel<<<NB, 256, 0, stream>>>(deg, rowptr, bsum);
    scan2_kernel<<<1, 64, 0, stream>>>(bsum);
    scan3_kernel<<<(NN + 255) / 256, 256, 0, stream>>>(rowptr, cursor, bsum);
    scatter_kernel<<<(NE + 255) / 256, 256, 0, stream>>>(
        esrc, edst, ea, cursor, src_perm, dst_perm, ea_bf);
    wconv_kernel<<<(NL * DD * ED + 255) / 256, 256, 0, stream>>>(We, wt_bf);
    w12conv_kernel<<<(NL * DD * DD + 255) / 256, 256, 0, stream>>>(W1, W2, w1t, w2t);

    const float* xcur = x0;
    for (int l = 0; l < NL; ++l) {
        hipMemsetAsync(agg, 0, (size_t)NN * DD * sizeof(float), stream);
        hipMemsetAsync(bns, 0, 2 * DD * sizeof(float), stream);
        edge_mfma_kernel<<<NE / 256, 256, 0, stream>>>(
            xcur, ea_bf, src_perm, dst_perm,
            wt_bf + (size_t)l * DD * ED, be + (size_t)l * DD, agg);
        mlp_mfma_kernel<<<(NN + 63) / 64, 256, 0, stream>>>(
            xcur, agg, agg,
            w1t + (size_t)l * DD * DD, w2t + (size_t)l * DD * DD,
            b1 + (size_t)l * DD, b2 + (size_t)l * DD, bns);
        float* xn = (l == NL - 1) ? out : xb;
        bn_apply<<<(NN * DD / 4 + 255) / 256, 256, 0, stream>>>(
            agg, bns, gamma + (size_t)l * DD, beta + (size_t)l * DD, xn);
        xcur = xn;
    }
}

// Round 6
// 714.265 us; speedup vs baseline: 8.8460x; 1.0312x over previous
//
#include <hip/hip_runtime.h>

#define NN 50000
#define NE 800000
#define DD 128
#define ED 32
#define NL 4
#define BN_EPS 1e-5f
#define SCAN_B 1024
#define NB ((NN + SCAN_B - 1) / SCAN_B)   // 49
#define EB 128                            // edges per block (edge kernel)
#define MR 32                             // rows per block (mlp kernel)

typedef __attribute__((ext_vector_type(8))) short bf16x8;
typedef __attribute__((ext_vector_type(4))) float f32x4;

__device__ __forceinline__ unsigned short f2bf(float f) {
    unsigned u = __float_as_uint(f);
    u += 0x7fffu + ((u >> 16) & 1u);
    return (unsigned short)(u >> 16);
}
__device__ __forceinline__ float bf2f(unsigned short h) {
    return __uint_as_float((unsigned)h << 16);
}

// ---------------- CSR build ----------------
__global__ __launch_bounds__(256) void hist_kernel(
    const int* __restrict__ edst, int* __restrict__ deg)
{
    const int e = blockIdx.x * 256 + threadIdx.x;
    if (e < NE) atomicAdd(&deg[edst[e]], 1);
}

__global__ __launch_bounds__(256) void scan1_kernel(
    const int* __restrict__ deg, int* __restrict__ rowptr, int* __restrict__ bsum)
{
    __shared__ int sh[256];
    const int t = threadIdx.x, b = blockIdx.x;
    const int base = b * SCAN_B + t * 4;
    int v[4];
#pragma unroll
    for (int j = 0; j < 4; ++j) {
        const int idx = base + j;
        v[j] = (idx < NN) ? deg[idx] : 0;
    }
    sh[t] = v[0] + v[1] + v[2] + v[3];
    __syncthreads();
    for (int off = 1; off < 256; off <<= 1) {
        const int val = (t >= off) ? sh[t - off] : 0;
        __syncthreads();
        sh[t] += val;
        __syncthreads();
    }
    int p = (t == 0) ? 0 : sh[t - 1];
#pragma unroll
    for (int j = 0; j < 4; ++j) {
        const int idx = base + j;
        if (idx < NN) rowptr[idx] = p;
        p += v[j];
    }
    if (t == 255) bsum[b] = sh[255];
}

__global__ void scan2_kernel(int* __restrict__ bsum)
{
    if (threadIdx.x == 0) {
        int acc = 0;
        for (int i = 0; i < NB; ++i) { const int v = bsum[i]; bsum[i] = acc; acc += v; }
    }
}

__global__ __launch_bounds__(256) void scan3_kernel(
    int* __restrict__ rowptr, int* __restrict__ cursor, const int* __restrict__ bsum)
{
    const int idx = blockIdx.x * 256 + threadIdx.x;
    if (idx < NN) {
        const int v = rowptr[idx] + bsum[idx / SCAN_B];
        rowptr[idx] = v;
        cursor[idx] = v;
    }
    if (idx == 0) rowptr[NN] = NE;
}

// scatter edges into dst-sorted order; (src,dst) packed int2 + bf16 edge_attr
__global__ __launch_bounds__(256) void scatter_kernel(
    const int* __restrict__ esrc, const int* __restrict__ edst,
    const float* __restrict__ ea, int* __restrict__ cursor,
    int2* __restrict__ sd_perm, unsigned short* __restrict__ ea_bf)
{
    const int e = blockIdx.x * 256 + threadIdx.x;
    if (e < NE) {
        const int d = edst[e];
        const int pos = atomicAdd(&cursor[d], 1);
        sd_perm[pos] = make_int2(esrc[e], d);
        const float* er = &ea[(size_t)e * ED];
        unsigned short* ob = &ea_bf[(size_t)pos * ED];
#pragma unroll
        for (int g = 0; g < 8; ++g) {
            const float4 v = *(const float4*)&er[g * 4];
            uint2 p;
            p.x = (unsigned)f2bf(v.x) | ((unsigned)f2bf(v.y) << 16);
            p.y = (unsigned)f2bf(v.z) | ((unsigned)f2bf(v.w) << 16);
            *(uint2*)&ob[g * 4] = p;
        }
    }
}

// W_edge [NL][ED][DD] f32 -> wtb bf16 [NL][DD][ED] (transposed, contiguous in K)
__global__ __launch_bounds__(256) void wconv_kernel(
    const float* __restrict__ We, unsigned short* __restrict__ wtb)
{
    const int tid = blockIdx.x * 256 + threadIdx.x;
    if (tid < NL * DD * ED) {
        const int l = tid / (DD * ED);
        const int r = tid % (DD * ED);
        const int c = r / ED, k = r % ED;
        wtb[tid] = f2bf(We[(size_t)l * ED * DD + k * DD + c]);
    }
}

// W1/W2 [NL][DD][DD] f32 ([k][n]) -> bf16 [NL][DD][DD] ([n][k])
__global__ __launch_bounds__(256) void w12conv_kernel(
    const float* __restrict__ W1, const float* __restrict__ W2,
    unsigned short* __restrict__ w1t, unsigned short* __restrict__ w2t)
{
    const int tid = blockIdx.x * 256 + threadIdx.x;
    if (tid < NL * DD * DD) {
        const int l = tid / (DD * DD);
        const int r = tid % (DD * DD);
        const int n = r / DD, k = r % DD;
        const size_t s = (size_t)l * DD * DD + k * DD + n;
        w1t[tid] = f2bf(W1[s]);
        w2t[tid] = f2bf(W2[s]);
    }
}

// ---------------- MFMA edge kernel ----------------
// EB=128 edges/block, 4 waves, 32 KB LDS -> 5 blocks/CU.
__global__ __launch_bounds__(256, 5) void edge_mfma_kernel(
    const float* __restrict__ x,
    const unsigned short* __restrict__ eab,   // [NE][ED] bf16, dst-sorted
    const int2* __restrict__ sd_perm,         // [NE] (src,dst), dst-sorted
    const unsigned short* __restrict__ wtb,   // [DD][ED] bf16 (layer slice)
    const float* __restrict__ be,
    float* __restrict__ agg)
{
    __shared__ unsigned short msgl[EB * 128];   // 32 KB
    const int t = threadIdx.x;
    const int wv = t >> 6, ln = t & 63;
    const int l15 = ln & 15, kb = ln >> 4;
    const int e0 = blockIdx.x * EB;

    const int c0 = (2 * wv + 0) * 16 + l15;
    const int c1 = (2 * wv + 1) * 16 + l15;
    const bf16x8 bfr0 = *(const bf16x8*)&wtb[c0 * ED + kb * 8];
    const bf16x8 bfr1 = *(const bf16x8*)&wtb[c1 * ED + kb * 8];

#pragma unroll
    for (int eg = 0; eg < EB / 16; ++eg) {
        const int edge = eg * 16 + l15;
        const bf16x8 afr = *(const bf16x8*)&eab[(size_t)(e0 + edge) * ED + kb * 8];
        f32x4 z = {0.f, 0.f, 0.f, 0.f};
        const f32x4 d0 = __builtin_amdgcn_mfma_f32_16x16x32_bf16(afr, bfr0, z, 0, 0, 0);
        const f32x4 d1 = __builtin_amdgcn_mfma_f32_16x16x32_bf16(afr, bfr1, z, 0, 0, 0);
#pragma unroll
        for (int j = 0; j < 4; ++j) {
            const int mrow = eg * 16 + kb * 4 + j;
            const int sw = ((mrow >> 2) & 3) << 3;
            const int i0 = (((c0 >> 1) ^ sw) << 1) | (c0 & 1);
            const int i1 = (((c1 >> 1) ^ sw) << 1) | (c1 & 1);
            msgl[mrow * 128 + i0] = f2bf(d0[j]);
            msgl[mrow * 128 + i1] = f2bf(d1[j]);
        }
    }
    __syncthreads();

    // Phase C: segmented reduce, 32 sorted edges per wave
    const int lbase = wv * 32;                 // edge offset within block
    const int2* sdp = &sd_perm[e0 + lbase];
    const int c2 = ln * 2;
    const float2 bv = *(const float2*)&be[c2];
    float2 acc = {0.f, 0.f};
    int seg_start = 0;
#pragma unroll 1
    for (int g = 0; g < 4; ++g) {
        const int gb = g * 8;
        int4 pr[4];
#pragma unroll
        for (int q = 0; q < 4; ++q)
            pr[q] = *(const int4*)&sdp[gb + 2 * q];
        const int srcs[8] = {pr[0].x, pr[0].z, pr[1].x, pr[1].z,
                             pr[2].x, pr[2].z, pr[3].x, pr[3].z};
        int dsts[9];
        dsts[0] = pr[0].y; dsts[1] = pr[0].w; dsts[2] = pr[1].y; dsts[3] = pr[1].w;
        dsts[4] = pr[2].y; dsts[5] = pr[2].w; dsts[6] = pr[3].y; dsts[7] = pr[3].w;
        dsts[8] = (gb + 8 < 32) ? sdp[gb + 8].y : -1;
        float2 xv[8];
#pragma unroll
        for (int q = 0; q < 8; ++q)
            xv[q] = *(const float2*)&x[(size_t)srcs[q] * DD + c2];
#pragma unroll
        for (int q = 0; q < 8; ++q) {
            const int i = gb + q;
            const int dw = ln ^ (((i >> 2) & 3) << 3);
            const unsigned mm = *(const unsigned*)&msgl[(lbase + i) * 128 + dw * 2];
            const float mlo = __uint_as_float(mm << 16);
            const float mhi = __uint_as_float(mm & 0xffff0000u);
            acc.x += fmaxf(xv[q].x + mlo + bv.x, 0.f);
            acc.y += fmaxf(xv[q].y + mhi + bv.y, 0.f);
            if (i == 31 || dsts[q + 1] != dsts[q]) {
                float* ap = &agg[(size_t)dsts[q] * DD + c2];
                if (seg_start > 0 && i < 31) {
                    *(float2*)ap = acc;             // interior: sole writer
                } else {
                    unsafeAtomicAdd(ap + 0, acc.x); // chunk-boundary segment
                    unsafeAtomicAdd(ap + 1, acc.y);
                }
                acc.x = 0.f; acc.y = 0.f;
                seg_start = i + 1;
            }
        }
    }
}

// ---------------- MFMA node MLP kernel ----------------
// MR=32 rows/block, 4 waves (wave owns 32 output cols), 32 KB LDS -> 5 blocks/CU.
// A (h, h1) staged as split bf16 (hi + lo residual), XOR-swizzled granules.
__global__ __launch_bounds__(256, 5) void mlp_mfma_kernel(
    const float* __restrict__ x, const float* __restrict__ agg,
    float* __restrict__ h2out,
    const unsigned short* __restrict__ w1t,   // [DD][DD] bf16 [n][k] (layer slice)
    const unsigned short* __restrict__ w2t,
    const float* __restrict__ b1, const float* __restrict__ b2,
    float* __restrict__ bns)
{
    __shared__ unsigned short ah[MR * 128];  // 8 KB h hi
    __shared__ unsigned short al[MR * 128];  // 8 KB h lo
    __shared__ unsigned short bh[MR * 128];  // 8 KB h1 hi
    __shared__ unsigned short bl[MR * 128];  // 8 KB h1 lo
    const int t = threadIdx.x;
    const int wv = t >> 6, ln = t & 63, l15 = ln & 15, kb = ln >> 4;
    const int r0 = blockIdx.x * MR;

    // ---- stage h = x + agg -> split bf16, swizzled (2 passes x 16 rows x 16 granules) ----
#pragma unroll
    for (int p = 0; p < 2; ++p) {
        const int row = p * 16 + (t >> 4);
        const int gc = t & 15;
        const int grow = r0 + row;
        float v[8] = {0.f, 0.f, 0.f, 0.f, 0.f, 0.f, 0.f, 0.f};
        if (grow < NN) {
            const size_t g = (size_t)grow * DD + gc * 8;
            const float4 xa = *(const float4*)&x[g];
            const float4 xc = *(const float4*)&x[g + 4];
            const float4 ga = *(const float4*)&agg[g];
            const float4 gc4 = *(const float4*)&agg[g + 4];
            v[0] = xa.x + ga.x; v[1] = xa.y + ga.y; v[2] = xa.z + ga.z; v[3] = xa.w + ga.w;
            v[4] = xc.x + gc4.x; v[5] = xc.y + gc4.y; v[6] = xc.z + gc4.z; v[7] = xc.w + gc4.w;
        }
        unsigned hiw[4], low[4];
#pragma unroll
        for (int j = 0; j < 4; ++j) {
            const unsigned short h0 = f2bf(v[2 * j]);
            const unsigned short h1 = f2bf(v[2 * j + 1]);
            const unsigned short q0 = f2bf(v[2 * j] - bf2f(h0));
            const unsigned short q1 = f2bf(v[2 * j + 1] - bf2f(h1));
            hiw[j] = (unsigned)h0 | ((unsigned)h1 << 16);
            low[j] = (unsigned)q0 | ((unsigned)q1 << 16);
        }
        const int off = row * 128 + (gc ^ (row & 7)) * 8;
        *(uint4*)&ah[off] = *(uint4*)hiw;
        *(uint4*)&al[off] = *(uint4*)low;
    }

    // B fragments for GEMM1
    bf16x8 w1f[2][4];
#pragma unroll
    for (int nt = 0; nt < 2; ++nt) {
        const int n = wv * 32 + nt * 16 + l15;
#pragma unroll
        for (int ks = 0; ks < 4; ++ks)
            w1f[nt][ks] = *(const bf16x8*)&w1t[n * DD + ks * 32 + kb * 8];
    }
    const int cA = wv * 32 + l15, cB = wv * 32 + 16 + l15;
    const float b1v[2] = {b1[cA], b1[cB]};
    const float b2v[2] = {b2[cA], b2[cB]};
    __syncthreads();

    // ---- GEMM1 ----
    f32x4 acc[2][2];
#pragma unroll
    for (int mt = 0; mt < 2; ++mt)
#pragma unroll
        for (int nt = 0; nt < 2; ++nt)
            acc[mt][nt] = (f32x4){0.f, 0.f, 0.f, 0.f};
#pragma unroll
    for (int ks = 0; ks < 4; ++ks) {
#pragma unroll
        for (int mt = 0; mt < 2; ++mt) {
            const int row = mt * 16 + l15;
            const int off = row * 128 + ((ks * 4 + kb) ^ (row & 7)) * 8;
            const bf16x8 afh = *(const bf16x8*)&ah[off];
            const bf16x8 afl = *(const bf16x8*)&al[off];
#pragma unroll
            for (int nt = 0; nt < 2; ++nt) {
                acc[mt][nt] = __builtin_amdgcn_mfma_f32_16x16x32_bf16(afh, w1f[nt][ks], acc[mt][nt], 0, 0, 0);
                acc[mt][nt] = __builtin_amdgcn_mfma_f32_16x16x32_bf16(afl, w1f[nt][ks], acc[mt][nt], 0, 0, 0);
            }
        }
    }

    // ---- h1 = relu(acc + b1) -> split bf16 LDS ----
#pragma unroll
    for (int mt = 0; mt < 2; ++mt) {
#pragma unroll
        for (int nt = 0; nt < 2; ++nt) {
            const int col = wv * 32 + nt * 16 + l15;
#pragma unroll
            for (int j = 0; j < 4; ++j) {
                const int row = mt * 16 + kb * 4 + j;
                const float v = fmaxf(acc[mt][nt][j] + b1v[nt], 0.f);
                const unsigned short hi = f2bf(v);
                const int off = row * 128 + ((col >> 3) ^ (row & 7)) * 8 + (col & 7);
                bh[off] = hi;
                bl[off] = f2bf(v - bf2f(hi));
            }
        }
    }

    // B fragments for GEMM2
    bf16x8 w2f[2][4];
#pragma unroll
    for (int nt = 0; nt < 2; ++nt) {
        const int n = wv * 32 + nt * 16 + l15;
#pragma unroll
        for (int ks = 0; ks < 4; ++ks)
            w2f[nt][ks] = *(const bf16x8*)&w2t[n * DD + ks * 32 + kb * 8];
    }
    __syncthreads();

    // ---- GEMM2 ----
#pragma unroll
    for (int mt = 0; mt < 2; ++mt)
#pragma unroll
        for (int nt = 0; nt < 2; ++nt)
            acc[mt][nt] = (f32x4){0.f, 0.f, 0.f, 0.f};
#pragma unroll
    for (int ks = 0; ks < 4; ++ks) {
#pragma unroll
        for (int mt = 0; mt < 2; ++mt) {
            const int row = mt * 16 + l15;
            const int off = row * 128 + ((ks * 4 + kb) ^ (row & 7)) * 8;
            const bf16x8 afh = *(const bf16x8*)&bh[off];
            const bf16x8 afl = *(const bf16x8*)&bl[off];
#pragma unroll
            for (int nt = 0; nt < 2; ++nt) {
                acc[mt][nt] = __builtin_amdgcn_mfma_f32_16x16x32_bf16(afh, w2f[nt][ks], acc[mt][nt], 0, 0, 0);
                acc[mt][nt] = __builtin_amdgcn_mfma_f32_16x16x32_bf16(afl, w2f[nt][ks], acc[mt][nt], 0, 0, 0);
            }
        }
    }

    // ---- epilogue: h2 store + BN partial sums ----
    float ps[2] = {0.f, 0.f}, pq[2] = {0.f, 0.f};
#pragma unroll
    for (int mt = 0; mt < 2; ++mt) {
#pragma unroll
        for (int nt = 0; nt < 2; ++nt) {
            const int col = wv * 32 + nt * 16 + l15;
#pragma unroll
            for (int j = 0; j < 4; ++j) {
                const int row = r0 + mt * 16 + kb * 4 + j;
                const float v = acc[mt][nt][j] + b2v[nt];
                if (row < NN) {
                    h2out[(size_t)row * DD + col] = v;
                    ps[nt] += v;
                    pq[nt] += v * v;
                }
            }
        }
    }
#pragma unroll
    for (int nt = 0; nt < 2; ++nt) {
        ps[nt] += __shfl_xor(ps[nt], 16);
        ps[nt] += __shfl_xor(ps[nt], 32);
        pq[nt] += __shfl_xor(pq[nt], 16);
        pq[nt] += __shfl_xor(pq[nt], 32);
    }
    if (kb == 0) {
#pragma unroll
        for (int nt = 0; nt < 2; ++nt) {
            const int col = wv * 32 + nt * 16 + l15;
            unsafeAtomicAdd(&bns[col], ps[nt]);
            unsafeAtomicAdd(&bns[DD + col], pq[nt]);
        }
    }
}

// ---------------- BN apply + ReLU ----------------
__global__ __launch_bounds__(256) void bn_apply(
    const float* __restrict__ h2, const float* __restrict__ bns,
    const float* __restrict__ gamma, const float* __restrict__ beta,
    float* __restrict__ xout)
{
    const size_t i = ((size_t)blockIdx.x * 256 + threadIdx.x) * 4;
    if (i >= (size_t)NN * DD) return;
    const int c4 = (int)(i & 127);
    const float4 hv = *(const float4*)&h2[i];
    const float4 sv = *(const float4*)&bns[c4];
    const float4 qv = *(const float4*)&bns[DD + c4];
    const float4 gv = *(const float4*)&gamma[c4];
    const float4 bv = *(const float4*)&beta[c4];
    const float inv_n = 1.f / (float)NN;
    float4 ov;
    {
        const float m = sv.x * inv_n;
        const float var = qv.x * inv_n - m * m;
        ov.x = fmaxf((hv.x - m) * __frsqrt_rn(var + BN_EPS) * gv.x + bv.x, 0.f);
    }
    {
        const float m = sv.y * inv_n;
        const float var = qv.y * inv_n - m * m;
        ov.y = fmaxf((hv.y - m) * __frsqrt_rn(var + BN_EPS) * gv.y + bv.y, 0.f);
    }
    {
        const float m = sv.z * inv_n;
        const float var = qv.z * inv_n - m * m;
        ov.z = fmaxf((hv.z - m) * __frsqrt_rn(var + BN_EPS) * gv.z + bv.z, 0.f);
    }
    {
        const float m = sv.w * inv_n;
        const float var = qv.w * inv_n - m * m;
        ov.w = fmaxf((hv.w - m) * __frsqrt_rn(var + BN_EPS) * gv.w + bv.w, 0.f);
    }
    *(float4*)&xout[i] = ov;
}

extern "C" void kernel_launch(void* const* d_in, const int* in_sizes, int n_in,
                              void* d_out, int out_size, void* d_ws, size_t ws_size,
                              hipStream_t stream) {
    const float* x0    = (const float*)d_in[0];
    const float* ea    = (const float*)d_in[1];
    const int*   eidx  = (const int*)d_in[2];
    const float* We    = (const float*)d_in[3];
    const float* be    = (const float*)d_in[4];
    const float* W1    = (const float*)d_in[5];
    const float* b1    = (const float*)d_in[6];
    const float* W2    = (const float*)d_in[7];
    const float* b2    = (const float*)d_in[8];
    const float* gamma = (const float*)d_in[9];
    const float* beta  = (const float*)d_in[10];
    float* out = (float*)d_out;
    float* ws  = (float*)d_ws;

    float* agg = ws;                              // NN*DD (doubles as h2)
    float* xb  = agg + (size_t)NN * DD;           // NN*DD
    float* bns = xb + (size_t)NN * DD;            // 256
    int* deg      = (int*)(bns + 256);            // 50000
    int* rowptr   = deg + 50000;                  // 50004 (padded)
    int* cursor   = rowptr + 50004;               // 50000
    int* bsum     = cursor + 50000;               // 64
    int2* sd_perm = (int2*)(bsum + 64);           // NE int2
    unsigned short* ea_bf = (unsigned short*)(sd_perm + NE);   // NE*ED
    unsigned short* wt_bf = ea_bf + (size_t)NE * ED;           // NL*DD*ED
    unsigned short* w1t   = wt_bf + (size_t)NL * DD * ED;      // NL*DD*DD
    unsigned short* w2t   = w1t + (size_t)NL * DD * DD;        // NL*DD*DD

    const int* esrc = eidx;
    const int* edst = eidx + NE;

    // ---- CSR build + bf16 pre-conversion (once; reused by all 4 layers) ----
    hipMemsetAsync(deg, 0, NN * sizeof(int), stream);
    hist_kernel<<<(NE + 255) / 256, 256, 0, stream>>>(edst, deg);
    scan1_kernel<<<NB, 256, 0, stream>>>(deg, rowptr, bsum);
    scan2_kernel<<<1, 64, 0, stream>>>(bsum);
    scan3_kernel<<<(NN + 255) / 256, 256, 0, stream>>>(rowptr, cursor, bsum);
    scatter_kernel<<<(NE + 255) / 256, 256, 0, stream>>>(
        esrc, edst, ea, cursor, sd_perm, ea_bf);
    wconv_kernel<<<(NL * DD * ED + 255) / 256, 256, 0, stream>>>(We, wt_bf);
    w12conv_kernel<<<(NL * DD * DD + 255) / 256, 256, 0, stream>>>(W1, W2, w1t, w2t);

    const float* xcur = x0;
    for (int l = 0; l < NL; ++l) {
        hipMemsetAsync(agg, 0, (size_t)NN * DD * sizeof(float), stream);
        hipMemsetAsync(bns, 0, 2 * DD * sizeof(float), stream);
        edge_mfma_kernel<<<NE / EB, 256, 0, stream>>>(
            xcur, ea_bf, sd_perm,
            wt_bf + (size_t)l * DD * ED, be + (size_t)l * DD, agg);
        mlp_mfma_kernel<<<(NN + MR - 1) / MR, 256, 0, stream>>>(
            xcur, agg, agg,
            w1t + (size_t)l * DD * DD, w2t + (size_t)l * DD * DD,
            b1 + (size_t)l * DD, b2 + (size_t)l * DD, bns);
        float* xn = (l == NL - 1) ? out : xb;
        bn_apply<<<(NN * DD / 4 + 255) / 256, 256, 0, stream>>>(
            agg, bns, gamma + (size_t)l * DD, beta + (size_t)l * DD, xn);
        xcur = xn;
    }
}

// Round 7
// 669.728 us; speedup vs baseline: 9.4343x; 1.0665x over previous
//
#include <hip/hip_runtime.h>

#define NN 50000
#define NE 800000
#define DD 128
#define ED 32
#define NL 4
#define BN_EPS 1e-5f
#define SCAN_B 1024
#define NB ((NN + SCAN_B - 1) / SCAN_B)   // 49
#define EB 128                            // edges per block (edge kernel)
#define MR 32                             // rows per block (mlp kernel)

typedef __attribute__((ext_vector_type(8))) short bf16x8;
typedef __attribute__((ext_vector_type(4))) float f32x4;

__device__ __forceinline__ unsigned short f2bf(float f) {
    unsigned u = __float_as_uint(f);
    u += 0x7fffu + ((u >> 16) & 1u);
    return (unsigned short)(u >> 16);
}
__device__ __forceinline__ float bf2f(unsigned short h) {
    return __uint_as_float((unsigned)h << 16);
}

// ---------------- CSR build ----------------
__global__ __launch_bounds__(256) void hist_kernel(
    const int* __restrict__ edst, int* __restrict__ deg)
{
    const int e = blockIdx.x * 256 + threadIdx.x;
    if (e < NE) atomicAdd(&deg[edst[e]], 1);
}

__global__ __launch_bounds__(256) void scan1_kernel(
    const int* __restrict__ deg, int* __restrict__ rowptr, int* __restrict__ bsum)
{
    __shared__ int sh[256];
    const int t = threadIdx.x, b = blockIdx.x;
    const int base = b * SCAN_B + t * 4;
    int v[4];
#pragma unroll
    for (int j = 0; j < 4; ++j) {
        const int idx = base + j;
        v[j] = (idx < NN) ? deg[idx] : 0;
    }
    sh[t] = v[0] + v[1] + v[2] + v[3];
    __syncthreads();
    for (int off = 1; off < 256; off <<= 1) {
        const int val = (t >= off) ? sh[t - off] : 0;
        __syncthreads();
        sh[t] += val;
        __syncthreads();
    }
    int p = (t == 0) ? 0 : sh[t - 1];
#pragma unroll
    for (int j = 0; j < 4; ++j) {
        const int idx = base + j;
        if (idx < NN) rowptr[idx] = p;
        p += v[j];
    }
    if (t == 255) bsum[b] = sh[255];
}

__global__ void scan2_kernel(int* __restrict__ bsum)
{
    if (threadIdx.x == 0) {
        int acc = 0;
        for (int i = 0; i < NB; ++i) { const int v = bsum[i]; bsum[i] = acc; acc += v; }
    }
}

__global__ __launch_bounds__(256) void scan3_kernel(
    int* __restrict__ rowptr, int* __restrict__ cursor, const int* __restrict__ bsum)
{
    const int idx = blockIdx.x * 256 + threadIdx.x;
    if (idx < NN) {
        const int v = rowptr[idx] + bsum[idx / SCAN_B];
        rowptr[idx] = v;
        cursor[idx] = v;
    }
    if (idx == 0) rowptr[NN] = NE;
}

// scatter only indices: (src,dst) pairs + edge-id permutation (light writes)
__global__ __launch_bounds__(256) void scatter_idx_kernel(
    const int* __restrict__ esrc, const int* __restrict__ edst,
    int* __restrict__ cursor, int2* __restrict__ sd_perm, int* __restrict__ eid_perm)
{
    const int e = blockIdx.x * 256 + threadIdx.x;
    if (e < NE) {
        const int d = edst[e];
        const int pos = atomicAdd(&cursor[d], 1);
        sd_perm[pos] = make_int2(esrc[e], d);
        eid_perm[pos] = e;
    }
}

// gather edge_attr into dst-sorted bf16: scattered 128B READS, coalesced writes
__global__ __launch_bounds__(256) void ea_gather_kernel(
    const float* __restrict__ ea, const int* __restrict__ eid_perm,
    unsigned short* __restrict__ ea_bf)
{
    const int tid = blockIdx.x * 256 + threadIdx.x;
    const int pos = tid >> 3, j = tid & 7;    // 8 lanes per edge row
    if (pos < NE) {
        const int e = eid_perm[pos];
        const float4 v = *(const float4*)&ea[(size_t)e * ED + j * 4];
        uint2 p;
        p.x = (unsigned)f2bf(v.x) | ((unsigned)f2bf(v.y) << 16);
        p.y = (unsigned)f2bf(v.z) | ((unsigned)f2bf(v.w) << 16);
        *(uint2*)&ea_bf[(size_t)pos * ED + j * 4] = p;
    }
}

// x0 f32 -> bf16 (once per call, feeds layer 0)
__global__ __launch_bounds__(256) void x0conv_kernel(
    const float* __restrict__ x0, unsigned short* __restrict__ xbf)
{
    const size_t i = ((size_t)blockIdx.x * 256 + threadIdx.x) * 8;
    if (i >= (size_t)NN * DD) return;
    const float4 a = *(const float4*)&x0[i];
    const float4 b = *(const float4*)&x0[i + 4];
    uint4 o;
    o.x = (unsigned)f2bf(a.x) | ((unsigned)f2bf(a.y) << 16);
    o.y = (unsigned)f2bf(a.z) | ((unsigned)f2bf(a.w) << 16);
    o.z = (unsigned)f2bf(b.x) | ((unsigned)f2bf(b.y) << 16);
    o.w = (unsigned)f2bf(b.z) | ((unsigned)f2bf(b.w) << 16);
    *(uint4*)&xbf[i] = o;
}

// W_edge [NL][ED][DD] f32 -> wtb bf16 [NL][DD][ED] (transposed, contiguous in K)
__global__ __launch_bounds__(256) void wconv_kernel(
    const float* __restrict__ We, unsigned short* __restrict__ wtb)
{
    const int tid = blockIdx.x * 256 + threadIdx.x;
    if (tid < NL * DD * ED) {
        const int l = tid / (DD * ED);
        const int r = tid % (DD * ED);
        const int c = r / ED, k = r % ED;
        wtb[tid] = f2bf(We[(size_t)l * ED * DD + k * DD + c]);
    }
}

// W1/W2 [NL][DD][DD] f32 ([k][n]) -> bf16 [NL][DD][DD] ([n][k])
__global__ __launch_bounds__(256) void w12conv_kernel(
    const float* __restrict__ W1, const float* __restrict__ W2,
    unsigned short* __restrict__ w1t, unsigned short* __restrict__ w2t)
{
    const int tid = blockIdx.x * 256 + threadIdx.x;
    if (tid < NL * DD * DD) {
        const int l = tid / (DD * DD);
        const int r = tid % (DD * DD);
        const int n = r / DD, k = r % DD;
        const size_t s = (size_t)l * DD * DD + k * DD + n;
        w1t[tid] = f2bf(W1[s]);
        w2t[tid] = f2bf(W2[s]);
    }
}

// ---------------- MFMA edge kernel ----------------
// EB=128 edges/block, 4 waves, 32 KB LDS -> 5 blocks/CU. x gathered as bf16.
__global__ __launch_bounds__(256, 5) void edge_mfma_kernel(
    const unsigned short* __restrict__ xbf,   // [NN][DD] bf16
    const unsigned short* __restrict__ eab,   // [NE][ED] bf16, dst-sorted
    const int2* __restrict__ sd_perm,         // [NE] (src,dst), dst-sorted
    const unsigned short* __restrict__ wtb,   // [DD][ED] bf16 (layer slice)
    const float* __restrict__ be,
    float* __restrict__ agg)
{
    __shared__ unsigned short msgl[EB * 128];   // 32 KB
    const int t = threadIdx.x;
    const int wv = t >> 6, ln = t & 63;
    const int l15 = ln & 15, kb = ln >> 4;
    const int e0 = blockIdx.x * EB;

    const int c0 = (2 * wv + 0) * 16 + l15;
    const int c1 = (2 * wv + 1) * 16 + l15;
    const bf16x8 bfr0 = *(const bf16x8*)&wtb[c0 * ED + kb * 8];
    const bf16x8 bfr1 = *(const bf16x8*)&wtb[c1 * ED + kb * 8];

#pragma unroll
    for (int eg = 0; eg < EB / 16; ++eg) {
        const int edge = eg * 16 + l15;
        const bf16x8 afr = *(const bf16x8*)&eab[(size_t)(e0 + edge) * ED + kb * 8];
        f32x4 z = {0.f, 0.f, 0.f, 0.f};
        const f32x4 d0 = __builtin_amdgcn_mfma_f32_16x16x32_bf16(afr, bfr0, z, 0, 0, 0);
        const f32x4 d1 = __builtin_amdgcn_mfma_f32_16x16x32_bf16(afr, bfr1, z, 0, 0, 0);
#pragma unroll
        for (int j = 0; j < 4; ++j) {
            const int mrow = eg * 16 + kb * 4 + j;
            const int sw = ((mrow >> 2) & 3) << 3;
            const int i0 = (((c0 >> 1) ^ sw) << 1) | (c0 & 1);
            const int i1 = (((c1 >> 1) ^ sw) << 1) | (c1 & 1);
            msgl[mrow * 128 + i0] = f2bf(d0[j]);
            msgl[mrow * 128 + i1] = f2bf(d1[j]);
        }
    }
    __syncthreads();

    // Phase C: segmented reduce, 32 sorted edges per wave
    const int lbase = wv * 32;
    const int2* sdp = &sd_perm[e0 + lbase];
    const int c2 = ln * 2;
    const float2 bv = *(const float2*)&be[c2];
    float2 acc = {0.f, 0.f};
    int seg_start = 0;
#pragma unroll 1
    for (int g = 0; g < 4; ++g) {
        const int gb = g * 8;
        int4 pr[4];
#pragma unroll
        for (int q = 0; q < 4; ++q)
            pr[q] = *(const int4*)&sdp[gb + 2 * q];
        const int srcs[8] = {pr[0].x, pr[0].z, pr[1].x, pr[1].z,
                             pr[2].x, pr[2].z, pr[3].x, pr[3].z};
        int dsts[9];
        dsts[0] = pr[0].y; dsts[1] = pr[0].w; dsts[2] = pr[1].y; dsts[3] = pr[1].w;
        dsts[4] = pr[2].y; dsts[5] = pr[2].w; dsts[6] = pr[3].y; dsts[7] = pr[3].w;
        dsts[8] = (gb + 8 < 32) ? sdp[gb + 8].y : -1;
        float2 xv[8];
#pragma unroll
        for (int q = 0; q < 8; ++q) {
            const unsigned xu = *(const unsigned*)&xbf[(size_t)srcs[q] * DD + c2];
            xv[q].x = __uint_as_float(xu << 16);
            xv[q].y = __uint_as_float(xu & 0xffff0000u);
        }
#pragma unroll
        for (int q = 0; q < 8; ++q) {
            const int i = gb + q;
            const int dw = ln ^ (((i >> 2) & 3) << 3);
            const unsigned mm = *(const unsigned*)&msgl[(lbase + i) * 128 + dw * 2];
            const float mlo = __uint_as_float(mm << 16);
            const float mhi = __uint_as_float(mm & 0xffff0000u);
            acc.x += fmaxf(xv[q].x + mlo + bv.x, 0.f);
            acc.y += fmaxf(xv[q].y + mhi + bv.y, 0.f);
            if (i == 31 || dsts[q + 1] != dsts[q]) {
                float* ap = &agg[(size_t)dsts[q] * DD + c2];
                if (seg_start > 0 && i < 31) {
                    *(float2*)ap = acc;             // interior: sole writer
                } else {
                    unsafeAtomicAdd(ap + 0, acc.x); // chunk-boundary segment
                    unsafeAtomicAdd(ap + 1, acc.y);
                }
                acc.x = 0.f; acc.y = 0.f;
                seg_start = i + 1;
            }
        }
    }
}

// ---------------- MFMA node MLP kernel ----------------
// MR=32 rows/block, 4 waves (wave owns 32 output cols), 32 KB LDS -> 5 blocks/CU.
// h = bf16(x) + f32 agg, staged as split bf16 (hi + lo residual), XOR-swizzled.
__global__ __launch_bounds__(256, 5) void mlp_mfma_kernel(
    const unsigned short* __restrict__ xbf, const float* __restrict__ agg,
    float* __restrict__ h2out,
    const unsigned short* __restrict__ w1t,   // [DD][DD] bf16 [n][k] (layer slice)
    const unsigned short* __restrict__ w2t,
    const float* __restrict__ b1, const float* __restrict__ b2,
    float* __restrict__ bns)
{
    __shared__ unsigned short ah[MR * 128];  // 8 KB h hi
    __shared__ unsigned short al[MR * 128];  // 8 KB h lo
    __shared__ unsigned short bh[MR * 128];  // 8 KB h1 hi
    __shared__ unsigned short bl[MR * 128];  // 8 KB h1 lo
    const int t = threadIdx.x;
    const int wv = t >> 6, ln = t & 63, l15 = ln & 15, kb = ln >> 4;
    const int r0 = blockIdx.x * MR;

    // ---- stage h = x + agg -> split bf16, swizzled (2 passes x 16 rows x 16 granules) ----
#pragma unroll
    for (int p = 0; p < 2; ++p) {
        const int row = p * 16 + (t >> 4);
        const int gc = t & 15;
        const int grow = r0 + row;
        float v[8] = {0.f, 0.f, 0.f, 0.f, 0.f, 0.f, 0.f, 0.f};
        if (grow < NN) {
            const size_t g = (size_t)grow * DD + gc * 8;
            const uint4 xu = *(const uint4*)&xbf[g];
            const float4 ga = *(const float4*)&agg[g];
            const float4 gb4 = *(const float4*)&agg[g + 4];
            v[0] = __uint_as_float(xu.x << 16)          + ga.x;
            v[1] = __uint_as_float(xu.x & 0xffff0000u)  + ga.y;
            v[2] = __uint_as_float(xu.y << 16)          + ga.z;
            v[3] = __uint_as_float(xu.y & 0xffff0000u)  + ga.w;
            v[4] = __uint_as_float(xu.z << 16)          + gb4.x;
            v[5] = __uint_as_float(xu.z & 0xffff0000u)  + gb4.y;
            v[6] = __uint_as_float(xu.w << 16)          + gb4.z;
            v[7] = __uint_as_float(xu.w & 0xffff0000u)  + gb4.w;
        }
        unsigned hiw[4], low[4];
#pragma unroll
        for (int j = 0; j < 4; ++j) {
            const unsigned short h0 = f2bf(v[2 * j]);
            const unsigned short h1 = f2bf(v[2 * j + 1]);
            const unsigned short q0 = f2bf(v[2 * j] - bf2f(h0));
            const unsigned short q1 = f2bf(v[2 * j + 1] - bf2f(h1));
            hiw[j] = (unsigned)h0 | ((unsigned)h1 << 16);
            low[j] = (unsigned)q0 | ((unsigned)q1 << 16);
        }
        const int off = row * 128 + (gc ^ (row & 7)) * 8;
        *(uint4*)&ah[off] = *(uint4*)hiw;
        *(uint4*)&al[off] = *(uint4*)low;
    }

    // B fragments for GEMM1
    bf16x8 w1f[2][4];
#pragma unroll
    for (int nt = 0; nt < 2; ++nt) {
        const int n = wv * 32 + nt * 16 + l15;
#pragma unroll
        for (int ks = 0; ks < 4; ++ks)
            w1f[nt][ks] = *(const bf16x8*)&w1t[n * DD + ks * 32 + kb * 8];
    }
    const int cA = wv * 32 + l15, cB = wv * 32 + 16 + l15;
    const float b1v[2] = {b1[cA], b1[cB]};
    const float b2v[2] = {b2[cA], b2[cB]};
    __syncthreads();

    // ---- GEMM1 ----
    f32x4 acc[2][2];
#pragma unroll
    for (int mt = 0; mt < 2; ++mt)
#pragma unroll
        for (int nt = 0; nt < 2; ++nt)
            acc[mt][nt] = (f32x4){0.f, 0.f, 0.f, 0.f};
#pragma unroll
    for (int ks = 0; ks < 4; ++ks) {
#pragma unroll
        for (int mt = 0; mt < 2; ++mt) {
            const int row = mt * 16 + l15;
            const int off = row * 128 + ((ks * 4 + kb) ^ (row & 7)) * 8;
            const bf16x8 afh = *(const bf16x8*)&ah[off];
            const bf16x8 afl = *(const bf16x8*)&al[off];
#pragma unroll
            for (int nt = 0; nt < 2; ++nt) {
                acc[mt][nt] = __builtin_amdgcn_mfma_f32_16x16x32_bf16(afh, w1f[nt][ks], acc[mt][nt], 0, 0, 0);
                acc[mt][nt] = __builtin_amdgcn_mfma_f32_16x16x32_bf16(afl, w1f[nt][ks], acc[mt][nt], 0, 0, 0);
            }
        }
    }

    // ---- h1 = relu(acc + b1) -> split bf16 LDS ----
#pragma unroll
    for (int mt = 0; mt < 2; ++mt) {
#pragma unroll
        for (int nt = 0; nt < 2; ++nt) {
            const int col = wv * 32 + nt * 16 + l15;
#pragma unroll
            for (int j = 0; j < 4; ++j) {
                const int row = mt * 16 + kb * 4 + j;
                const float v = fmaxf(acc[mt][nt][j] + b1v[nt], 0.f);
                const unsigned short hi = f2bf(v);
                const int off = row * 128 + ((col >> 3) ^ (row & 7)) * 8 + (col & 7);
                bh[off] = hi;
                bl[off] = f2bf(v - bf2f(hi));
            }
        }
    }

    // B fragments for GEMM2
    bf16x8 w2f[2][4];
#pragma unroll
    for (int nt = 0; nt < 2; ++nt) {
        const int n = wv * 32 + nt * 16 + l15;
#pragma unroll
        for (int ks = 0; ks < 4; ++ks)
            w2f[nt][ks] = *(const bf16x8*)&w2t[n * DD + ks * 32 + kb * 8];
    }
    __syncthreads();

    // ---- GEMM2 ----
#pragma unroll
    for (int mt = 0; mt < 2; ++mt)
#pragma unroll
        for (int nt = 0; nt < 2; ++nt)
            acc[mt][nt] = (f32x4){0.f, 0.f, 0.f, 0.f};
#pragma unroll
    for (int ks = 0; ks < 4; ++ks) {
#pragma unroll
        for (int mt = 0; mt < 2; ++mt) {
            const int row = mt * 16 + l15;
            const int off = row * 128 + ((ks * 4 + kb) ^ (row & 7)) * 8;
            const bf16x8 afh = *(const bf16x8*)&bh[off];
            const bf16x8 afl = *(const bf16x8*)&bl[off];
#pragma unroll
            for (int nt = 0; nt < 2; ++nt) {
                acc[mt][nt] = __builtin_amdgcn_mfma_f32_16x16x32_bf16(afh, w2f[nt][ks], acc[mt][nt], 0, 0, 0);
                acc[mt][nt] = __builtin_amdgcn_mfma_f32_16x16x32_bf16(afl, w2f[nt][ks], acc[mt][nt], 0, 0, 0);
            }
        }
    }

    // ---- epilogue: h2 store + BN partial sums ----
    float ps[2] = {0.f, 0.f}, pq[2] = {0.f, 0.f};
#pragma unroll
    for (int mt = 0; mt < 2; ++mt) {
#pragma unroll
        for (int nt = 0; nt < 2; ++nt) {
            const int col = wv * 32 + nt * 16 + l15;
#pragma unroll
            for (int j = 0; j < 4; ++j) {
                const int row = r0 + mt * 16 + kb * 4 + j;
                const float v = acc[mt][nt][j] + b2v[nt];
                if (row < NN) {
                    h2out[(size_t)row * DD + col] = v;
                    ps[nt] += v;
                    pq[nt] += v * v;
                }
            }
        }
    }
#pragma unroll
    for (int nt = 0; nt < 2; ++nt) {
        ps[nt] += __shfl_xor(ps[nt], 16);
        ps[nt] += __shfl_xor(ps[nt], 32);
        pq[nt] += __shfl_xor(pq[nt], 16);
        pq[nt] += __shfl_xor(pq[nt], 32);
    }
    if (kb == 0) {
#pragma unroll
        for (int nt = 0; nt < 2; ++nt) {
            const int col = wv * 32 + nt * 16 + l15;
            unsafeAtomicAdd(&bns[col], ps[nt]);
            unsafeAtomicAdd(&bns[DD + col], pq[nt]);
        }
    }
}

// ---------------- BN apply + ReLU -> bf16 x (layers 0..2) ----------------
__global__ __launch_bounds__(256) void bn_apply_bf16(
    const float* __restrict__ h2, const float* __restrict__ bns,
    const float* __restrict__ gamma, const float* __restrict__ beta,
    unsigned short* __restrict__ xout)
{
    const size_t i = ((size_t)blockIdx.x * 256 + threadIdx.x) * 4;
    if (i >= (size_t)NN * DD) return;
    const int c4 = (int)(i & 127);
    const float4 hv = *(const float4*)&h2[i];
    const float4 sv = *(const float4*)&bns[c4];
    const float4 qv = *(const float4*)&bns[DD + c4];
    const float4 gv = *(const float4*)&gamma[c4];
    const float4 bv = *(const float4*)&beta[c4];
    const float inv_n = 1.f / (float)NN;
    float o0, o1, o2, o3;
    { const float m = sv.x * inv_n; const float var = qv.x * inv_n - m * m;
      o0 = fmaxf((hv.x - m) * __frsqrt_rn(var + BN_EPS) * gv.x + bv.x, 0.f); }
    { const float m = sv.y * inv_n; const float var = qv.y * inv_n - m * m;
      o1 = fmaxf((hv.y - m) * __frsqrt_rn(var + BN_EPS) * gv.y + bv.y, 0.f); }
    { const float m = sv.z * inv_n; const float var = qv.z * inv_n - m * m;
      o2 = fmaxf((hv.z - m) * __frsqrt_rn(var + BN_EPS) * gv.z + bv.z, 0.f); }
    { const float m = sv.w * inv_n; const float var = qv.w * inv_n - m * m;
      o3 = fmaxf((hv.w - m) * __frsqrt_rn(var + BN_EPS) * gv.w + bv.w, 0.f); }
    uint2 o;
    o.x = (unsigned)f2bf(o0) | ((unsigned)f2bf(o1) << 16);
    o.y = (unsigned)f2bf(o2) | ((unsigned)f2bf(o3) << 16);
    *(uint2*)&xout[i] = o;
}

// ---------------- BN apply + ReLU -> f32 out (final layer) ----------------
__global__ __launch_bounds__(256) void bn_apply_f32(
    const float* __restrict__ h2, const float* __restrict__ bns,
    const float* __restrict__ gamma, const float* __restrict__ beta,
    float* __restrict__ xout)
{
    const size_t i = ((size_t)blockIdx.x * 256 + threadIdx.x) * 4;
    if (i >= (size_t)NN * DD) return;
    const int c4 = (int)(i & 127);
    const float4 hv = *(const float4*)&h2[i];
    const float4 sv = *(const float4*)&bns[c4];
    const float4 qv = *(const float4*)&bns[DD + c4];
    const float4 gv = *(const float4*)&gamma[c4];
    const float4 bv = *(const float4*)&beta[c4];
    const float inv_n = 1.f / (float)NN;
    float4 ov;
    { const float m = sv.x * inv_n; const float var = qv.x * inv_n - m * m;
      ov.x = fmaxf((hv.x - m) * __frsqrt_rn(var + BN_EPS) * gv.x + bv.x, 0.f); }
    { const float m = sv.y * inv_n; const float var = qv.y * inv_n - m * m;
      ov.y = fmaxf((hv.y - m) * __frsqrt_rn(var + BN_EPS) * gv.y + bv.y, 0.f); }
    { const float m = sv.z * inv_n; const float var = qv.z * inv_n - m * m;
      ov.z = fmaxf((hv.z - m) * __frsqrt_rn(var + BN_EPS) * gv.z + bv.z, 0.f); }
    { const float m = sv.w * inv_n; const float var = qv.w * inv_n - m * m;
      ov.w = fmaxf((hv.w - m) * __frsqrt_rn(var + BN_EPS) * gv.w + bv.w, 0.f); }
    *(float4*)&xout[i] = ov;
}

extern "C" void kernel_launch(void* const* d_in, const int* in_sizes, int n_in,
                              void* d_out, int out_size, void* d_ws, size_t ws_size,
                              hipStream_t stream) {
    const float* x0    = (const float*)d_in[0];
    const float* ea    = (const float*)d_in[1];
    const int*   eidx  = (const int*)d_in[2];
    const float* We    = (const float*)d_in[3];
    const float* be    = (const float*)d_in[4];
    const float* W1    = (const float*)d_in[5];
    const float* b1    = (const float*)d_in[6];
    const float* W2    = (const float*)d_in[7];
    const float* b2    = (const float*)d_in[8];
    const float* gamma = (const float*)d_in[9];
    const float* beta  = (const float*)d_in[10];
    float* out = (float*)d_out;
    float* ws  = (float*)d_ws;

    float* agg = ws;                              // NN*DD f32 (doubles as h2)
    float* bns = agg + (size_t)NN * DD;           // 256
    int* deg      = (int*)(bns + 256);            // 50000
    int* rowptr   = deg + 50000;                  // 50004 (padded)
    int* cursor   = rowptr + 50004;               // 50000
    int* bsum     = cursor + 50000;               // 64
    int2* sd_perm = (int2*)(bsum + 64);           // NE int2
    int* eid_perm = (int*)(sd_perm + NE);         // NE
    unsigned short* ea_bf = (unsigned short*)(eid_perm + NE);  // NE*ED
    unsigned short* wt_bf = ea_bf + (size_t)NE * ED;           // NL*DD*ED
    unsigned short* w1t   = wt_bf + (size_t)NL * DD * ED;      // NL*DD*DD
    unsigned short* w2t   = w1t + (size_t)NL * DD * DD;        // NL*DD*DD
    unsigned short* xbf   = w2t + (size_t)NL * DD * DD;        // NN*DD bf16

    const int* esrc = eidx;
    const int* edst = eidx + NE;

    // ---- CSR build + bf16 pre-conversion (once; reused by all 4 layers) ----
    hipMemsetAsync(deg, 0, NN * sizeof(int), stream);
    hist_kernel<<<(NE + 255) / 256, 256, 0, stream>>>(edst, deg);
    scan1_kernel<<<NB, 256, 0, stream>>>(deg, rowptr, bsum);
    scan2_kernel<<<1, 64, 0, stream>>>(bsum);
    scan3_kernel<<<(NN + 255) / 256, 256, 0, stream>>>(rowptr, cursor, bsum);
    scatter_idx_kernel<<<(NE + 255) / 256, 256, 0, stream>>>(
        esrc, edst, cursor, sd_perm, eid_perm);
    ea_gather_kernel<<<(NE * 8 + 255) / 256, 256, 0, stream>>>(ea, eid_perm, ea_bf);
    x0conv_kernel<<<((NN * DD / 8) + 255) / 256, 256, 0, stream>>>(x0, xbf);
    wconv_kernel<<<(NL * DD * ED + 255) / 256, 256, 0, stream>>>(We, wt_bf);
    w12conv_kernel<<<(NL * DD * DD + 255) / 256, 256, 0, stream>>>(W1, W2, w1t, w2t);

    for (int l = 0; l < NL; ++l) {
        hipMemsetAsync(agg, 0, (size_t)NN * DD * sizeof(float), stream);
        hipMemsetAsync(bns, 0, 2 * DD * sizeof(float), stream);
        edge_mfma_kernel<<<NE / EB, 256, 0, stream>>>(
            xbf, ea_bf, sd_perm,
            wt_bf + (size_t)l * DD * ED, be + (size_t)l * DD, agg);
        mlp_mfma_kernel<<<(NN + MR - 1) / MR, 256, 0, stream>>>(
            xbf, agg, agg,
            w1t + (size_t)l * DD * DD, w2t + (size_t)l * DD * DD,
            b1 + (size_t)l * DD, b2 + (size_t)l * DD, bns);
        if (l < NL - 1) {
            bn_apply_bf16<<<(NN * DD / 4 + 255) / 256, 256, 0, stream>>>(
                agg, bns, gamma + (size_t)l * DD, beta + (size_t)l * DD, xbf);
        } else {
            bn_apply_f32<<<(NN * DD / 4 + 255) / 256, 256, 0, stream>>>(
                agg, bns, gamma + (size_t)l * DD, beta + (size_t)l * DD, out);
        }
    }
}

// Round 8
// 650.313 us; speedup vs baseline: 9.7159x; 1.0299x over previous
//
#include <hip/hip_runtime.h>

#define NN 50000
#define NE 800000
#define DD 128
#define ED 32
#define NL 4
#define BN_EPS 1e-5f
#define SCAN_B 1024
#define NB ((NN + SCAN_B - 1) / SCAN_B)   // 49
#define EB 128                            // edges per block (edge kernel)
#define MR 32                             // rows per block (mlp kernel)

typedef __attribute__((ext_vector_type(8))) short bf16x8;
typedef __attribute__((ext_vector_type(4))) float f32x4;

__device__ __forceinline__ unsigned short f2bf(float f) {
    unsigned u = __float_as_uint(f);
    u += 0x7fffu + ((u >> 16) & 1u);
    return (unsigned short)(u >> 16);
}
__device__ __forceinline__ float bf2f(unsigned short h) {
    return __uint_as_float((unsigned)h << 16);
}

// ---------------- CSR build ----------------
__global__ __launch_bounds__(256) void hist_kernel(
    const int* __restrict__ edst, int* __restrict__ deg)
{
    const int e = blockIdx.x * 256 + threadIdx.x;
    if (e < NE) atomicAdd(&deg[edst[e]], 1);
}

__global__ __launch_bounds__(256) void scan1_kernel(
    const int* __restrict__ deg, int* __restrict__ rowptr, int* __restrict__ bsum)
{
    __shared__ int sh[256];
    const int t = threadIdx.x, b = blockIdx.x;
    const int base = b * SCAN_B + t * 4;
    int v[4];
#pragma unroll
    for (int j = 0; j < 4; ++j) {
        const int idx = base + j;
        v[j] = (idx < NN) ? deg[idx] : 0;
    }
    sh[t] = v[0] + v[1] + v[2] + v[3];
    __syncthreads();
    for (int off = 1; off < 256; off <<= 1) {
        const int val = (t >= off) ? sh[t - off] : 0;
        __syncthreads();
        sh[t] += val;
        __syncthreads();
    }
    int p = (t == 0) ? 0 : sh[t - 1];
#pragma unroll
    for (int j = 0; j < 4; ++j) {
        const int idx = base + j;
        if (idx < NN) rowptr[idx] = p;
        p += v[j];
    }
    if (t == 255) bsum[b] = sh[255];
}

__global__ void scan2_kernel(int* __restrict__ bsum)
{
    if (threadIdx.x == 0) {
        int acc = 0;
        for (int i = 0; i < NB; ++i) { const int v = bsum[i]; bsum[i] = acc; acc += v; }
    }
}

__global__ __launch_bounds__(256) void scan3_kernel(
    int* __restrict__ rowptr, int* __restrict__ cursor, const int* __restrict__ bsum)
{
    const int idx = blockIdx.x * 256 + threadIdx.x;
    if (idx < NN) {
        const int v = rowptr[idx] + bsum[idx / SCAN_B];
        rowptr[idx] = v;
        cursor[idx] = v;
    }
    if (idx == 0) rowptr[NN] = NE;
}

// scatter only the edge-id permutation (4B scattered writes — minimal RMW amp)
__global__ __launch_bounds__(256) void scatter_idx_kernel(
    const int* __restrict__ edst, int* __restrict__ cursor, int* __restrict__ eid_perm)
{
    const int e = blockIdx.x * 256 + threadIdx.x;
    if (e < NE) {
        const int pos = atomicAdd(&cursor[edst[e]], 1);
        eid_perm[pos] = e;
    }
}

// fill (src,dst) pairs per node span: per-thread sequential writes (L2 write-combine)
__global__ __launch_bounds__(256) void sdfill_kernel(
    const int* __restrict__ rowptr, const int* __restrict__ eid_perm,
    const int* __restrict__ esrc, int2* __restrict__ sd_perm)
{
    const int d = blockIdx.x * 256 + threadIdx.x;
    if (d < NN) {
        const int b = rowptr[d], e = rowptr[d + 1];
        for (int p = b; p < e; ++p)
            sd_perm[p] = make_int2(esrc[eid_perm[p]], d);
    }
}

// gather edge_attr into dst-sorted bf16: scattered 128B READS, coalesced writes
__global__ __launch_bounds__(256) void ea_gather_kernel(
    const float* __restrict__ ea, const int* __restrict__ eid_perm,
    unsigned short* __restrict__ ea_bf)
{
    const int tid = blockIdx.x * 256 + threadIdx.x;
    const int pos = tid >> 3, j = tid & 7;    // 8 lanes per edge row
    if (pos < NE) {
        const int e = eid_perm[pos];
        const float4 v = *(const float4*)&ea[(size_t)e * ED + j * 4];
        uint2 p;
        p.x = (unsigned)f2bf(v.x) | ((unsigned)f2bf(v.y) << 16);
        p.y = (unsigned)f2bf(v.z) | ((unsigned)f2bf(v.w) << 16);
        *(uint2*)&ea_bf[(size_t)pos * ED + j * 4] = p;
    }
}

// x0 f32 -> bf16 (once per call, feeds layer 0)
__global__ __launch_bounds__(256) void x0conv_kernel(
    const float* __restrict__ x0, unsigned short* __restrict__ xbf)
{
    const size_t i = ((size_t)blockIdx.x * 256 + threadIdx.x) * 8;
    if (i >= (size_t)NN * DD) return;
    const float4 a = *(const float4*)&x0[i];
    const float4 b = *(const float4*)&x0[i + 4];
    uint4 o;
    o.x = (unsigned)f2bf(a.x) | ((unsigned)f2bf(a.y) << 16);
    o.y = (unsigned)f2bf(a.z) | ((unsigned)f2bf(a.w) << 16);
    o.z = (unsigned)f2bf(b.x) | ((unsigned)f2bf(b.y) << 16);
    o.w = (unsigned)f2bf(b.z) | ((unsigned)f2bf(b.w) << 16);
    *(uint4*)&xbf[i] = o;
}

// W_edge [NL][ED][DD] f32 -> wtb bf16 [NL][DD][ED] (transposed, contiguous in K)
__global__ __launch_bounds__(256) void wconv_kernel(
    const float* __restrict__ We, unsigned short* __restrict__ wtb)
{
    const int tid = blockIdx.x * 256 + threadIdx.x;
    if (tid < NL * DD * ED) {
        const int l = tid / (DD * ED);
        const int r = tid % (DD * ED);
        const int c = r / ED, k = r % ED;
        wtb[tid] = f2bf(We[(size_t)l * ED * DD + k * DD + c]);
    }
}

// W1/W2 [NL][DD][DD] f32 ([k][n]) -> bf16 [NL][DD][DD] ([n][k])
__global__ __launch_bounds__(256) void w12conv_kernel(
    const float* __restrict__ W1, const float* __restrict__ W2,
    unsigned short* __restrict__ w1t, unsigned short* __restrict__ w2t)
{
    const int tid = blockIdx.x * 256 + threadIdx.x;
    if (tid < NL * DD * DD) {
        const int l = tid / (DD * DD);
        const int r = tid % (DD * DD);
        const int n = r / DD, k = r % DD;
        const size_t s = (size_t)l * DD * DD + k * DD + n;
        w1t[tid] = f2bf(W1[s]);
        w2t[tid] = f2bf(W2[s]);
    }
}

// ---------------- MFMA edge kernel ----------------
// EB=128 edges/block, 4 waves, 32 KB LDS -> 5 blocks/CU.
// Phase C: 2x16-edge halves with all index+gather loads issued up front (ILP).
__global__ __launch_bounds__(256, 5) void edge_mfma_kernel(
    const unsigned short* __restrict__ xbf,   // [NN][DD] bf16
    const unsigned short* __restrict__ eab,   // [NE][ED] bf16, dst-sorted
    const int2* __restrict__ sd_perm,         // [NE] (src,dst), dst-sorted
    const unsigned short* __restrict__ wtb,   // [DD][ED] bf16 (layer slice)
    const float* __restrict__ be,
    float* __restrict__ agg)
{
    __shared__ unsigned short msgl[EB * 128];   // 32 KB
    const int t = threadIdx.x;
    const int wv = t >> 6, ln = t & 63;
    const int l15 = ln & 15, kb = ln >> 4;
    const int e0 = blockIdx.x * EB;

    const int c0 = (2 * wv + 0) * 16 + l15;
    const int c1 = (2 * wv + 1) * 16 + l15;
    const bf16x8 bfr0 = *(const bf16x8*)&wtb[c0 * ED + kb * 8];
    const bf16x8 bfr1 = *(const bf16x8*)&wtb[c1 * ED + kb * 8];

#pragma unroll
    for (int eg = 0; eg < EB / 16; ++eg) {
        const int edge = eg * 16 + l15;
        const bf16x8 afr = *(const bf16x8*)&eab[(size_t)(e0 + edge) * ED + kb * 8];
        f32x4 z = {0.f, 0.f, 0.f, 0.f};
        const f32x4 d0 = __builtin_amdgcn_mfma_f32_16x16x32_bf16(afr, bfr0, z, 0, 0, 0);
        const f32x4 d1 = __builtin_amdgcn_mfma_f32_16x16x32_bf16(afr, bfr1, z, 0, 0, 0);
#pragma unroll
        for (int j = 0; j < 4; ++j) {
            const int mrow = eg * 16 + kb * 4 + j;
            const int sw = ((mrow >> 2) & 3) << 3;
            const int i0 = (((c0 >> 1) ^ sw) << 1) | (c0 & 1);
            const int i1 = (((c1 >> 1) ^ sw) << 1) | (c1 & 1);
            msgl[mrow * 128 + i0] = f2bf(d0[j]);
            msgl[mrow * 128 + i1] = f2bf(d1[j]);
        }
    }
    __syncthreads();

    // Phase C: segmented reduce, 32 sorted edges per wave (2 halves of 16)
    const int lbase = wv * 32;
    const int2* sdp = &sd_perm[e0 + lbase];
    const int c2 = ln * 2;
    const float2 bv = *(const float2*)&be[c2];
    float2 acc = {0.f, 0.f};
    int seg_start = 0;
#pragma unroll 1
    for (int g = 0; g < 2; ++g) {
        const int gb = g * 16;
        int4 pr[8];
#pragma unroll
        for (int q = 0; q < 8; ++q)
            pr[q] = *(const int4*)&sdp[gb + 2 * q];
        int srcs[16], dsts[17];
#pragma unroll
        for (int q = 0; q < 8; ++q) {
            srcs[2 * q] = pr[q].x; srcs[2 * q + 1] = pr[q].z;
            dsts[2 * q] = pr[q].y; dsts[2 * q + 1] = pr[q].w;
        }
        dsts[16] = (gb + 16 < 32) ? sdp[gb + 16].y : -1;
        float2 xv[16];
#pragma unroll
        for (int q = 0; q < 16; ++q) {
            const unsigned xu = *(const unsigned*)&xbf[(size_t)srcs[q] * DD + c2];
            xv[q].x = __uint_as_float(xu << 16);
            xv[q].y = __uint_as_float(xu & 0xffff0000u);
        }
#pragma unroll
        for (int q = 0; q < 16; ++q) {
            const int i = gb + q;
            const int dw = ln ^ (((i >> 2) & 3) << 3);
            const unsigned mm = *(const unsigned*)&msgl[(lbase + i) * 128 + dw * 2];
            const float mlo = __uint_as_float(mm << 16);
            const float mhi = __uint_as_float(mm & 0xffff0000u);
            acc.x += fmaxf(xv[q].x + mlo + bv.x, 0.f);
            acc.y += fmaxf(xv[q].y + mhi + bv.y, 0.f);
            if (i == 31 || dsts[q + 1] != dsts[q]) {
                float* ap = &agg[(size_t)dsts[q] * DD + c2];
                if (seg_start > 0 && i < 31) {
                    *(float2*)ap = acc;             // interior: sole writer
                } else {
                    unsafeAtomicAdd(ap + 0, acc.x); // chunk-boundary segment
                    unsafeAtomicAdd(ap + 1, acc.y);
                }
                acc.x = 0.f; acc.y = 0.f;
                seg_start = i + 1;
            }
        }
    }
}

// ---------------- MFMA node MLP kernel ----------------
// MR=32 rows/block, 4 waves (wave owns 32 output cols), 32 KB LDS -> 5 blocks/CU.
// h = bf16(x) + f32 agg, staged as split bf16 (hi + lo residual), XOR-swizzled.
__global__ __launch_bounds__(256, 5) void mlp_mfma_kernel(
    const unsigned short* __restrict__ xbf, const float* __restrict__ agg,
    float* __restrict__ h2out,
    const unsigned short* __restrict__ w1t,   // [DD][DD] bf16 [n][k] (layer slice)
    const unsigned short* __restrict__ w2t,
    const float* __restrict__ b1, const float* __restrict__ b2,
    float* __restrict__ bns)
{
    __shared__ unsigned short ah[MR * 128];  // 8 KB h hi
    __shared__ unsigned short al[MR * 128];  // 8 KB h lo
    __shared__ unsigned short bh[MR * 128];  // 8 KB h1 hi
    __shared__ unsigned short bl[MR * 128];  // 8 KB h1 lo
    const int t = threadIdx.x;
    const int wv = t >> 6, ln = t & 63, l15 = ln & 15, kb = ln >> 4;
    const int r0 = blockIdx.x * MR;

    // ---- stage h = x + agg -> split bf16, swizzled (2 passes x 16 rows x 16 granules) ----
#pragma unroll
    for (int p = 0; p < 2; ++p) {
        const int row = p * 16 + (t >> 4);
        const int gc = t & 15;
        const int grow = r0 + row;
        float v[8] = {0.f, 0.f, 0.f, 0.f, 0.f, 0.f, 0.f, 0.f};
        if (grow < NN) {
            const size_t g = (size_t)grow * DD + gc * 8;
            const uint4 xu = *(const uint4*)&xbf[g];
            const float4 ga = *(const float4*)&agg[g];
            const float4 gb4 = *(const float4*)&agg[g + 4];
            v[0] = __uint_as_float(xu.x << 16)          + ga.x;
            v[1] = __uint_as_float(xu.x & 0xffff0000u)  + ga.y;
            v[2] = __uint_as_float(xu.y << 16)          + ga.z;
            v[3] = __uint_as_float(xu.y & 0xffff0000u)  + ga.w;
            v[4] = __uint_as_float(xu.z << 16)          + gb4.x;
            v[5] = __uint_as_float(xu.z & 0xffff0000u)  + gb4.y;
            v[6] = __uint_as_float(xu.w << 16)          + gb4.z;
            v[7] = __uint_as_float(xu.w & 0xffff0000u)  + gb4.w;
        }
        unsigned hiw[4], low[4];
#pragma unroll
        for (int j = 0; j < 4; ++j) {
            const unsigned short h0 = f2bf(v[2 * j]);
            const unsigned short h1 = f2bf(v[2 * j + 1]);
            const unsigned short q0 = f2bf(v[2 * j] - bf2f(h0));
            const unsigned short q1 = f2bf(v[2 * j + 1] - bf2f(h1));
            hiw[j] = (unsigned)h0 | ((unsigned)h1 << 16);
            low[j] = (unsigned)q0 | ((unsigned)q1 << 16);
        }
        const int off = row * 128 + (gc ^ (row & 7)) * 8;
        *(uint4*)&ah[off] = *(uint4*)hiw;
        *(uint4*)&al[off] = *(uint4*)low;
    }

    // B fragments for GEMM1
    bf16x8 w1f[2][4];
#pragma unroll
    for (int nt = 0; nt < 2; ++nt) {
        const int n = wv * 32 + nt * 16 + l15;
#pragma unroll
        for (int ks = 0; ks < 4; ++ks)
            w1f[nt][ks] = *(const bf16x8*)&w1t[n * DD + ks * 32 + kb * 8];
    }
    const int cA = wv * 32 + l15, cB = wv * 32 + 16 + l15;
    const float b1v[2] = {b1[cA], b1[cB]};
    const float b2v[2] = {b2[cA], b2[cB]};
    __syncthreads();

    // ---- GEMM1 ----
    f32x4 acc[2][2];
#pragma unroll
    for (int mt = 0; mt < 2; ++mt)
#pragma unroll
        for (int nt = 0; nt < 2; ++nt)
            acc[mt][nt] = (f32x4){0.f, 0.f, 0.f, 0.f};
#pragma unroll
    for (int ks = 0; ks < 4; ++ks) {
#pragma unroll
        for (int mt = 0; mt < 2; ++mt) {
            const int row = mt * 16 + l15;
            const int off = row * 128 + ((ks * 4 + kb) ^ (row & 7)) * 8;
            const bf16x8 afh = *(const bf16x8*)&ah[off];
            const bf16x8 afl = *(const bf16x8*)&al[off];
#pragma unroll
            for (int nt = 0; nt < 2; ++nt) {
                acc[mt][nt] = __builtin_amdgcn_mfma_f32_16x16x32_bf16(afh, w1f[nt][ks], acc[mt][nt], 0, 0, 0);
                acc[mt][nt] = __builtin_amdgcn_mfma_f32_16x16x32_bf16(afl, w1f[nt][ks], acc[mt][nt], 0, 0, 0);
            }
        }
    }

    // ---- h1 = relu(acc + b1) -> split bf16 LDS ----
#pragma unroll
    for (int mt = 0; mt < 2; ++mt) {
#pragma unroll
        for (int nt = 0; nt < 2; ++nt) {
            const int col = wv * 32 + nt * 16 + l15;
#pragma unroll
            for (int j = 0; j < 4; ++j) {
                const int row = mt * 16 + kb * 4 + j;
                const float v = fmaxf(acc[mt][nt][j] + b1v[nt], 0.f);
                const unsigned short hi = f2bf(v);
                const int off = row * 128 + ((col >> 3) ^ (row & 7)) * 8 + (col & 7);
                bh[off] = hi;
                bl[off] = f2bf(v - bf2f(hi));
            }
        }
    }

    // B fragments for GEMM2
    bf16x8 w2f[2][4];
#pragma unroll
    for (int nt = 0; nt < 2; ++nt) {
        const int n = wv * 32 + nt * 16 + l15;
#pragma unroll
        for (int ks = 0; ks < 4; ++ks)
            w2f[nt][ks] = *(const bf16x8*)&w2t[n * DD + ks * 32 + kb * 8];
    }
    __syncthreads();

    // ---- GEMM2 ----
#pragma unroll
    for (int mt = 0; mt < 2; ++mt)
#pragma unroll
        for (int nt = 0; nt < 2; ++nt)
            acc[mt][nt] = (f32x4){0.f, 0.f, 0.f, 0.f};
#pragma unroll
    for (int ks = 0; ks < 4; ++ks) {
#pragma unroll
        for (int mt = 0; mt < 2; ++mt) {
            const int row = mt * 16 + l15;
            const int off = row * 128 + ((ks * 4 + kb) ^ (row & 7)) * 8;
            const bf16x8 afh = *(const bf16x8*)&bh[off];
            const bf16x8 afl = *(const bf16x8*)&bl[off];
#pragma unroll
            for (int nt = 0; nt < 2; ++nt) {
                acc[mt][nt] = __builtin_amdgcn_mfma_f32_16x16x32_bf16(afh, w2f[nt][ks], acc[mt][nt], 0, 0, 0);
                acc[mt][nt] = __builtin_amdgcn_mfma_f32_16x16x32_bf16(afl, w2f[nt][ks], acc[mt][nt], 0, 0, 0);
            }
        }
    }

    // ---- epilogue: h2 store + BN partial sums ----
    float ps[2] = {0.f, 0.f}, pq[2] = {0.f, 0.f};
#pragma unroll
    for (int mt = 0; mt < 2; ++mt) {
#pragma unroll
        for (int nt = 0; nt < 2; ++nt) {
            const int col = wv * 32 + nt * 16 + l15;
#pragma unroll
            for (int j = 0; j < 4; ++j) {
                const int row = r0 + mt * 16 + kb * 4 + j;
                const float v = acc[mt][nt][j] + b2v[nt];
                if (row < NN) {
                    h2out[(size_t)row * DD + col] = v;
                    ps[nt] += v;
                    pq[nt] += v * v;
                }
            }
        }
    }
#pragma unroll
    for (int nt = 0; nt < 2; ++nt) {
        ps[nt] += __shfl_xor(ps[nt], 16);
        ps[nt] += __shfl_xor(ps[nt], 32);
        pq[nt] += __shfl_xor(pq[nt], 16);
        pq[nt] += __shfl_xor(pq[nt], 32);
    }
    if (kb == 0) {
#pragma unroll
        for (int nt = 0; nt < 2; ++nt) {
            const int col = wv * 32 + nt * 16 + l15;
            unsafeAtomicAdd(&bns[col], ps[nt]);
            unsafeAtomicAdd(&bns[DD + col], pq[nt]);
        }
    }
}

// ---------------- BN apply + ReLU -> bf16 x; also zeroes agg for next layer ----------------
__global__ __launch_bounds__(256) void bn_apply_bf16(
    float* __restrict__ h2, const float* __restrict__ bns,
    const float* __restrict__ gamma, const float* __restrict__ beta,
    unsigned short* __restrict__ xout)
{
    const size_t i = ((size_t)blockIdx.x * 256 + threadIdx.x) * 4;
    if (i >= (size_t)NN * DD) return;
    const int c4 = (int)(i & 127);
    const float4 hv = *(const float4*)&h2[i];
    const float4 sv = *(const float4*)&bns[c4];
    const float4 qv = *(const float4*)&bns[DD + c4];
    const float4 gv = *(const float4*)&gamma[c4];
    const float4 bv = *(const float4*)&beta[c4];
    const float inv_n = 1.f / (float)NN;
    float o0, o1, o2, o3;
    { const float m = sv.x * inv_n; const float var = qv.x * inv_n - m * m;
      o0 = fmaxf((hv.x - m) * __frsqrt_rn(var + BN_EPS) * gv.x + bv.x, 0.f); }
    { const float m = sv.y * inv_n; const float var = qv.y * inv_n - m * m;
      o1 = fmaxf((hv.y - m) * __frsqrt_rn(var + BN_EPS) * gv.y + bv.y, 0.f); }
    { const float m = sv.z * inv_n; const float var = qv.z * inv_n - m * m;
      o2 = fmaxf((hv.z - m) * __frsqrt_rn(var + BN_EPS) * gv.z + bv.z, 0.f); }
    { const float m = sv.w * inv_n; const float var = qv.w * inv_n - m * m;
      o3 = fmaxf((hv.w - m) * __frsqrt_rn(var + BN_EPS) * gv.w + bv.w, 0.f); }
    uint2 o;
    o.x = (unsigned)f2bf(o0) | ((unsigned)f2bf(o1) << 16);
    o.y = (unsigned)f2bf(o2) | ((unsigned)f2bf(o3) << 16);
    *(uint2*)&xout[i] = o;
    *(float4*)&h2[i] = (float4){0.f, 0.f, 0.f, 0.f};   // fused agg zeroing
}

// ---------------- BN apply + ReLU -> f32 out (final layer) ----------------
__global__ __launch_bounds__(256) void bn_apply_f32(
    const float* __restrict__ h2, const float* __restrict__ bns,
    const float* __restrict__ gamma, const float* __restrict__ beta,
    float* __restrict__ xout)
{
    const size_t i = ((size_t)blockIdx.x * 256 + threadIdx.x) * 4;
    if (i >= (size_t)NN * DD) return;
    const int c4 = (int)(i & 127);
    const float4 hv = *(const float4*)&h2[i];
    const float4 sv = *(const float4*)&bns[c4];
    const float4 qv = *(const float4*)&bns[DD + c4];
    const float4 gv = *(const float4*)&gamma[c4];
    const float4 bv = *(const float4*)&beta[c4];
    const float inv_n = 1.f / (float)NN;
    float4 ov;
    { const float m = sv.x * inv_n; const float var = qv.x * inv_n - m * m;
      ov.x = fmaxf((hv.x - m) * __frsqrt_rn(var + BN_EPS) * gv.x + bv.x, 0.f); }
    { const float m = sv.y * inv_n; const float var = qv.y * inv_n - m * m;
      ov.y = fmaxf((hv.y - m) * __frsqrt_rn(var + BN_EPS) * gv.y + bv.y, 0.f); }
    { const float m = sv.z * inv_n; const float var = qv.z * inv_n - m * m;
      ov.z = fmaxf((hv.z - m) * __frsqrt_rn(var + BN_EPS) * gv.z + bv.z, 0.f); }
    { const float m = sv.w * inv_n; const float var = qv.w * inv_n - m * m;
      ov.w = fmaxf((hv.w - m) * __frsqrt_rn(var + BN_EPS) * gv.w + bv.w, 0.f); }
    *(float4*)&xout[i] = ov;
}

extern "C" void kernel_launch(void* const* d_in, const int* in_sizes, int n_in,
                              void* d_out, int out_size, void* d_ws, size_t ws_size,
                              hipStream_t stream) {
    const float* x0    = (const float*)d_in[0];
    const float* ea    = (const float*)d_in[1];
    const int*   eidx  = (const int*)d_in[2];
    const float* We    = (const float*)d_in[3];
    const float* be    = (const float*)d_in[4];
    const float* W1    = (const float*)d_in[5];
    const float* b1    = (const float*)d_in[6];
    const float* W2    = (const float*)d_in[7];
    const float* b2    = (const float*)d_in[8];
    const float* gamma = (const float*)d_in[9];
    const float* beta  = (const float*)d_in[10];
    float* out = (float*)d_out;
    float* ws  = (float*)d_ws;

    float* agg = ws;                              // NN*DD f32 (doubles as h2)
    float* bns = agg + (size_t)NN * DD;           // NL*256
    int* deg      = (int*)(bns + NL * 256);       // 50000
    int* rowptr   = deg + 50000;                  // 50004 (padded)
    int* cursor   = rowptr + 50004;               // 50000
    int* bsum     = cursor + 50000;               // 64
    int2* sd_perm = (int2*)(bsum + 64);           // NE int2
    int* eid_perm = (int*)(sd_perm + NE);         // NE
    unsigned short* ea_bf = (unsigned short*)(eid_perm + NE);  // NE*ED
    unsigned short* wt_bf = ea_bf + (size_t)NE * ED;           // NL*DD*ED
    unsigned short* w1t   = wt_bf + (size_t)NL * DD * ED;      // NL*DD*DD
    unsigned short* w2t   = w1t + (size_t)NL * DD * DD;        // NL*DD*DD
    unsigned short* xbf   = w2t + (size_t)NL * DD * DD;        // NN*DD bf16

    const int* esrc = eidx;
    const int* edst = eidx + NE;

    // ---- CSR build + bf16 pre-conversion (once; reused by all 4 layers) ----
    hipMemsetAsync(deg, 0, NN * sizeof(int), stream);
    hipMemsetAsync(bns, 0, NL * 256 * sizeof(float), stream);
    hipMemsetAsync(agg, 0, (size_t)NN * DD * sizeof(float), stream);
    hist_kernel<<<(NE + 255) / 256, 256, 0, stream>>>(edst, deg);
    scan1_kernel<<<NB, 256, 0, stream>>>(deg, rowptr, bsum);
    scan2_kernel<<<1, 64, 0, stream>>>(bsum);
    scan3_kernel<<<(NN + 255) / 256, 256, 0, stream>>>(rowptr, cursor, bsum);
    scatter_idx_kernel<<<(NE + 255) / 256, 256, 0, stream>>>(edst, cursor, eid_perm);
    sdfill_kernel<<<(NN + 255) / 256, 256, 0, stream>>>(rowptr, eid_perm, esrc, sd_perm);
    ea_gather_kernel<<<(NE * 8 + 255) / 256, 256, 0, stream>>>(ea, eid_perm, ea_bf);
    x0conv_kernel<<<((NN * DD / 8) + 255) / 256, 256, 0, stream>>>(x0, xbf);
    wconv_kernel<<<(NL * DD * ED + 255) / 256, 256, 0, stream>>>(We, wt_bf);
    w12conv_kernel<<<(NL * DD * DD + 255) / 256, 256, 0, stream>>>(W1, W2, w1t, w2t);

    for (int l = 0; l < NL; ++l) {
        edge_mfma_kernel<<<NE / EB, 256, 0, stream>>>(
            xbf, ea_bf, sd_perm,
            wt_bf + (size_t)l * DD * ED, be + (size_t)l * DD, agg);
        mlp_mfma_kernel<<<(NN + MR - 1) / MR, 256, 0, stream>>>(
            xbf, agg, agg,
            w1t + (size_t)l * DD * DD, w2t + (size_t)l * DD * DD,
            b1 + (size_t)l * DD, b2 + (size_t)l * DD, bns + l * 256);
        if (l < NL - 1) {
            bn_apply_bf16<<<(NN * DD / 4 + 255) / 256, 256, 0, stream>>>(
                agg, bns + l * 256, gamma + (size_t)l * DD, beta + (size_t)l * DD, xbf);
        } else {
            bn_apply_f32<<<(NN * DD / 4 + 255) / 256, 256, 0, stream>>>(
                agg, bns + l * 256, gamma + (size_t)l * DD, beta + (size_t)l * DD, out);
        }
    }
}